// Round 12
// baseline (363.421 us; speedup 1.0000x reference)
//
#include <hip/hip_runtime.h>
#include <math.h>

// Problem constants
#define L_DIM 4096
#define B_DIM 4
#define H_DIM 512
#define E_DIM 1024
#define S_DIM 128
#define HALF  64
#define N_ROWS 16384
#define NUV   2176
#define LN_EPS 1e-5f
#define INV_SQRT_S 0.08838834764831845f

typedef _Float16 f16;
typedef __attribute__((ext_vector_type(8))) _Float16 half8;
typedef __attribute__((ext_vector_type(4))) _Float16 half4;
typedef __attribute__((ext_vector_type(4))) float f32x4;

// fast silu: v_exp_f32 + v_rcp_f32 — safe only with VGPR pinned (LB 256,4)
__device__ __forceinline__ float fast_silu(float s) {
    return s * __builtin_amdgcn_rcpf(1.f + __expf(-s));
}

// ---------------- workspace byte offsets ----------------
// kc1 aliases ONLY xn (dead after uv; both touched solely via
// global_load_lds / plain stores). cos/sin are de-aliased (plain-load read).
#define OFF_WUV  ((size_t)0)                        // f16 [2176][512]   2.2 MB
#define OFF_WO   (OFF_WUV + 2228224)                // f16 [512][1024]   1 MB
#define OFF_U    (OFF_WO + 1048576)                 // f16 [16384][1024] 32 MB
#define OFF_VT   (OFF_U + 33554432)                 // f16 [4][1024][4096] 32 MB
#define OFF_AUB  (OFF_VT + 33554432)                // f16 [16384][1024] 32 MB
#define OFF_Q    (OFF_AUB + 33554432)               // f16 [16384][128]  4 MB
#define OFF_K    (OFF_Q + 4194304)                  // f16 [16384][128]  4 MB
#define OFF_KC0  (OFF_K + 4194304)                  // f16 [4][1024][4096] 32 MB
#define OFF_KC1  (OFF_KC0 + 33554432)               // f16 [4][1024][4096] 32 MB
#define OFF_XN   OFF_KC1                            // f16 [16384][512] (aliased)
#define OFF_COS  (OFF_KC1 + 33554432)               // f32 [4096][64]   1 MB
#define OFF_SIN  (OFF_COS + 1048576)                // f32 [4096][64]   1 MB
// end = OFF_SIN + 1MB = 181,534,720 B = 173.1 MiB (< proven 186.1)

// ---------------- RoPE cos/sin tables ----------------
__global__ void k_tables(float* __restrict__ cosT, float* __restrict__ sinT) {
    int idx = blockIdx.x * 256 + threadIdx.x;
    if (idx >= L_DIM * HALF) return;
    int pos = idx >> 6;
    int j = idx & 63;
    float invf = (float)pow(10000.0, (double)j / 64.0);
    float angf = (float)pos * invf;
    double ang = (double)angf;
    cosT[idx] = (float)cos(ang);
    sinT[idx] = (float)sin(ang);
}

// ---------------- fused LN stats + apply + f16 convert (1 wave / row) ------
__global__ __launch_bounds__(256) void k_xn(const float* __restrict__ x,
                                            const float* __restrict__ lnw,
                                            const float* __restrict__ lnb,
                                            f16* __restrict__ xn) {
    int row = blockIdx.x * 4 + (threadIdx.x >> 6);
    int lane = threadIdx.x & 63;
    const float4* xr = (const float4*)(x + (size_t)row * H_DIM);
    float4 a = xr[lane * 2], b = xr[lane * 2 + 1];
    float s = a.x + a.y + a.z + a.w + b.x + b.y + b.z + b.w;
    float s2 = a.x * a.x + a.y * a.y + a.z * a.z + a.w * a.w
             + b.x * b.x + b.y * b.y + b.z * b.z + b.w * b.w;
#pragma unroll
    for (int off = 32; off > 0; off >>= 1) {
        s  += __shfl_xor(s, off);
        s2 += __shfl_xor(s2, off);
    }
    float m = s / (float)H_DIM;
    float var = s2 / (float)H_DIM - m * m;
    float r = rsqrtf(var + LN_EPS);
    const float4* wr4 = (const float4*)lnw;
    const float4* br4 = (const float4*)lnb;
    float4 wa = wr4[lane * 2], wb = wr4[lane * 2 + 1];
    float4 ba = br4[lane * 2], bb = br4[lane * 2 + 1];
    half8 o;
    o[0] = (f16)((a.x - m) * r * wa.x + ba.x);
    o[1] = (f16)((a.y - m) * r * wa.y + ba.y);
    o[2] = (f16)((a.z - m) * r * wa.z + ba.z);
    o[3] = (f16)((a.w - m) * r * wa.w + ba.w);
    o[4] = (f16)((b.x - m) * r * wb.x + bb.x);
    o[5] = (f16)((b.y - m) * r * wb.y + bb.y);
    o[6] = (f16)((b.z - m) * r * wb.z + bb.z);
    o[7] = (f16)((b.w - m) * r * wb.w + bb.w);
    *(half8*)(xn + (size_t)row * H_DIM + lane * 8) = o;
}

// ---------------- weight conversion (uv_w then o_w) ----------------
__global__ __launch_bounds__(256) void k_cvt_w(const float* __restrict__ uvw,
                                               const float* __restrict__ ow,
                                               f16* __restrict__ duv,
                                               f16* __restrict__ dow) {
    int gid = blockIdx.x * 256 + threadIdx.x;
    int i4 = gid << 2;
    const float* src;
    f16* dst;
    int off;
    if (i4 < NUV * H_DIM) { src = uvw; dst = duv; off = i4; }
    else { src = ow; dst = dow; off = i4 - NUV * H_DIM; }
    float4 v = *(const float4*)(src + off);
    half4 o = {(f16)v.x, (f16)v.y, (f16)v.z, (f16)v.w};
    *(half4*)(dst + off) = o;
}

// ---------------- MFMA cores: C = A · B^T (both K-major f16) ----------------
__device__ __forceinline__ void gload16(const void* g, void* l) {
    __builtin_amdgcn_global_load_lds(
        (const __attribute__((address_space(1))) unsigned int*)g,
        (__attribute__((address_space(3))) unsigned int*)l, 16, 0, 0);
}

// Single-buffer core (hoisted addressing) — for uv (4 blocks/CU) & qk.
template <int MT, int NT>
__device__ __forceinline__ void mfma_core(const char* Ab, int lda_b,
                                          const char* Bb, int ldb_b,
                                          int K, f16* lds, f32x4 acc[MT][NT]) {
    constexpr int BM = 32 * MT, BN = 32 * NT;
    constexpr int ISS = (BM + BN) / 32;
    constexpr int ASLOTS = (BM * 128) / 1024;
    const int tid = threadIdx.x;
    const int lane = tid & 63;
    const int wv = tid >> 6;
    const int wr = wv >> 1, wc = wv & 1;
    char* ldsc = (char*)lds;

    const char* sb[ISS];
    unsigned voff[ISS];
#pragma unroll
    for (int i = 0; i < ISS; ++i) {
        const int slot = wv * ISS + i;
        const int ell = (slot << 10) + (lane << 4);
        if (slot < ASLOTS) {
            int row = ell >> 7, kb = ell & 127;
            sb[i] = Ab;
            voff[i] = (unsigned)row * (unsigned)lda_b + (unsigned)(kb ^ ((row & 7) << 4));
        } else {
            const int e2 = ell - BM * 128;
            int row = e2 >> 7, kb = e2 & 127;
            sb[i] = Bb;
            voff[i] = (unsigned)row * (unsigned)ldb_b + (unsigned)(kb ^ ((row & 7) << 4));
        }
    }
    unsigned aoff[MT], boff[NT];
#pragma unroll
    for (int mt = 0; mt < MT; ++mt) {
        int row = wr * (MT * 16) + mt * 16 + (lane & 15);
        unsigned byt = (unsigned)((row << 7) + ((lane >> 4) << 4));
        aoff[mt] = byt ^ (unsigned)((row & 7) << 4);
    }
#pragma unroll
    for (int nt = 0; nt < NT; ++nt) {
        int row = wc * (NT * 16) + nt * 16 + (lane & 15);
        unsigned byt = (unsigned)((row << 7) + ((lane >> 4) << 4));
        boff[nt] = (byt ^ (unsigned)((row & 7) << 4)) + (unsigned)(BM * 128);
    }

    for (int k0 = 0; k0 < K; k0 += 64) {
        const unsigned kbyte = (unsigned)(k0 << 1);
#pragma unroll
        for (int i = 0; i < ISS; ++i)
            gload16(sb[i] + voff[i] + kbyte, ldsc + ((wv * ISS + i) << 10));
        __syncthreads();
#pragma unroll
        for (int ks = 0; ks < 2; ++ks) {
            half8 af[MT], bf[NT];
#pragma unroll
            for (int mt = 0; mt < MT; ++mt)
                af[mt] = *(const half8*)(ldsc + (aoff[mt] ^ (unsigned)(ks << 6)));
#pragma unroll
            for (int nt = 0; nt < NT; ++nt)
                bf[nt] = *(const half8*)(ldsc + (boff[nt] ^ (unsigned)(ks << 6)));
#pragma unroll
            for (int mt = 0; mt < MT; ++mt)
#pragma unroll
                for (int nt = 0; nt < NT; ++nt)
                    acc[mt][nt] = __builtin_amdgcn_mfma_f32_16x16x32_f16(af[mt], bf[nt], acc[mt][nt], 0, 0, 0);
        }
        __syncthreads();
    }
}

// 2-phase dbuf core (r8-proven, A+B staged) — for av & out.
template <int MT, int NT>
__device__ __forceinline__ void mfma_core_db(const char* Ab, int lda_b,
                                             const char* Bb, int ldb_b,
                                             int K, char* l0, char* l1,
                                             f32x4 acc[MT][NT]) {
    constexpr int BM = 32 * MT, BN = 32 * NT;
    constexpr int ISS = (BM + BN) / 32;
    constexpr int ASLOTS = (BM * 128) / 1024;
    const int tid = threadIdx.x;
    const int lane = tid & 63;
    const int wv = tid >> 6;
    const int wr = wv >> 1, wc = wv & 1;

    const char* sb[ISS];
    unsigned voff[ISS];
#pragma unroll
    for (int i = 0; i < ISS; ++i) {
        const int slot = wv * ISS + i;
        const int ell = (slot << 10) + (lane << 4);
        if (slot < ASLOTS) {
            int row = ell >> 7, kb = ell & 127;
            sb[i] = Ab;
            voff[i] = (unsigned)row * (unsigned)lda_b + (unsigned)(kb ^ ((row & 7) << 4));
        } else {
            const int e2 = ell - BM * 128;
            int row = e2 >> 7, kb = e2 & 127;
            sb[i] = Bb;
            voff[i] = (unsigned)row * (unsigned)ldb_b + (unsigned)(kb ^ ((row & 7) << 4));
        }
    }
    unsigned aoff[MT], boff[NT];
#pragma unroll
    for (int mt = 0; mt < MT; ++mt) {
        int row = wr * (MT * 16) + mt * 16 + (lane & 15);
        unsigned byt = (unsigned)((row << 7) + ((lane >> 4) << 4));
        aoff[mt] = byt ^ (unsigned)((row & 7) << 4);
    }
#pragma unroll
    for (int nt = 0; nt < NT; ++nt) {
        int row = wc * (NT * 16) + nt * 16 + (lane & 15);
        unsigned byt = (unsigned)((row << 7) + ((lane >> 4) << 4));
        boff[nt] = (byt ^ (unsigned)((row & 7) << 4)) + (unsigned)(BM * 128);
    }

    auto stage = [&](char* dst, unsigned kbyte) {
#pragma unroll
        for (int i = 0; i < ISS; ++i)
            gload16(sb[i] + voff[i] + kbyte, dst + ((wv * ISS + i) << 10));
    };
    auto compute = [&](const char* src) {
#pragma unroll
        for (int ks = 0; ks < 2; ++ks) {
            half8 af[MT], bf[NT];
#pragma unroll
            for (int mt = 0; mt < MT; ++mt)
                af[mt] = *(const half8*)(src + (aoff[mt] ^ (unsigned)(ks << 6)));
#pragma unroll
            for (int nt = 0; nt < NT; ++nt)
                bf[nt] = *(const half8*)(src + (boff[nt] ^ (unsigned)(ks << 6)));
#pragma unroll
            for (int mt = 0; mt < MT; ++mt)
#pragma unroll
                for (int nt = 0; nt < NT; ++nt)
                    acc[mt][nt] = __builtin_amdgcn_mfma_f32_16x16x32_f16(af[mt], bf[nt], acc[mt][nt], 0, 0, 0);
        }
    };

    const int nst = K / 64;  // even
    stage(l0, 0u);
    __syncthreads();
    for (int t = 0; t < nst; t += 2) {
        stage(l1, (unsigned)(t + 1) * 128u);   // prefetch t+1 while computing t
        compute(l0);
        __syncthreads();
        if (t + 2 < nst) stage(l0, (unsigned)(t + 2) * 128u);
        compute(l1);
        __syncthreads();
    }
}

// ---------------- GEMM 1: silu(LN(x)@uv_w^T + b) -> u | vT | q,k (fused) ---
__global__ __launch_bounds__(256, 4) void k_mm_uv(const f16* __restrict__ xn,
                                                  const f16* __restrict__ wuv,
                                                  const float* __restrict__ bias,
                                                  f16* __restrict__ u,
                                                  f16* __restrict__ vT,
                                                  const float* __restrict__ gamma,
                                                  const float* __restrict__ beta,
                                                  const float* __restrict__ cosT,
                                                  const float* __restrict__ sinT,
                                                  f16* __restrict__ q,
                                                  f16* __restrict__ kq) {
    __shared__ union {
        f16 stage[256 * 64];
        f16 tr[128][136];
    } sl;
    const int m0 = blockIdx.y * 128, n0 = blockIdx.x * 128;
    f32x4 acc[4][4];
#pragma unroll
    for (int i = 0; i < 4; ++i)
#pragma unroll
        for (int j = 0; j < 4; ++j) acc[i][j] = (f32x4){0.f, 0.f, 0.f, 0.f};
    mfma_core<4, 4>((const char*)(xn + (size_t)m0 * H_DIM), H_DIM * 2,
                    (const char*)(wuv + (size_t)n0 * H_DIM), H_DIM * 2,
                    H_DIM, sl.stage, acc);
    const int lane = threadIdx.x & 63, wv = threadIdx.x >> 6;
    const int wr = wv >> 1, wc = wv & 1;
    if (n0 < E_DIM) {  // u region -> LDS tile -> coalesced wide stores
#pragma unroll
        for (int nt = 0; nt < 4; ++nt) {
            int nl = wc * 64 + nt * 16 + (lane & 15);
            float bs = bias[n0 + nl];
#pragma unroll
            for (int mt = 0; mt < 4; ++mt)
#pragma unroll
                for (int r = 0; r < 4; ++r) {
                    int ml = wr * 64 + mt * 16 + (lane >> 4) * 4 + r;
                    sl.tr[ml][nl] = (f16)fast_silu(acc[mt][nt][r] + bs);
                }
        }
        __syncthreads();
        int rl = threadIdx.x >> 1, h = threadIdx.x & 1;
        f16* dst = u + (size_t)(m0 + rl) * E_DIM + n0 + h * 64;
#pragma unroll
        for (int i = 0; i < 8; ++i)
            *(uint4*)(dst + i * 8) = *(const uint4*)&sl.tr[rl][h * 64 + i * 8];
    } else if (n0 < 2 * E_DIM) {  // v region -> transposed store via LDS
#pragma unroll
        for (int nt = 0; nt < 4; ++nt) {
            int nl = wc * 64 + nt * 16 + (lane & 15);
            float bs = bias[n0 + nl];
#pragma unroll
            for (int mt = 0; mt < 4; ++mt)
#pragma unroll
                for (int r = 0; r < 4; ++r) {
                    int ml = wr * 64 + mt * 16 + (lane >> 4) * 4 + r;
                    sl.tr[nl][ml] = (f16)fast_silu(acc[mt][nt][r] + bs);
                }
        }
        __syncthreads();
        int rl = threadIdx.x >> 1, h = threadIdx.x & 1;
        int b = m0 >> 12;
        int mloc = m0 & (L_DIM - 1);
        size_t e = (size_t)(n0 - E_DIM) + rl;
        f16* dst = vT + ((size_t)b * E_DIM + e) * L_DIM + mloc + h * 64;
#pragma unroll
        for (int i = 0; i < 8; ++i)
            *(uint4*)(dst + i * 8) = *(const uint4*)&sl.tr[rl][h * 64 + i * 8];
    } else {  // s region -> fused gamma/beta + RoPE -> q, k
#pragma unroll
        for (int nt = 0; nt < 4; ++nt) {
            int nl = wc * 64 + nt * 16 + (lane & 15);
            float bs = bias[n0 + nl];
#pragma unroll
            for (int mt = 0; mt < 4; ++mt)
#pragma unroll
                for (int r = 0; r < 4; ++r) {
                    int ml = wr * 64 + mt * 16 + (lane >> 4) * 4 + r;
                    sl.tr[ml][nl] = (f16)fast_silu(acc[mt][nt][r] + bs);
                }
        }
        __syncthreads();
        const int rl = threadIdx.x >> 1, h = threadIdx.x & 1;
        const int row = m0 + rl;
        const int l = row & (L_DIM - 1);
        const float* cT = cosT + l * HALF + h * 32;
        const float* sT = sinT + l * HALF + h * 32;
        f16* qp = q + (size_t)row * S_DIM + h * 32;
        f16* kp = kq + (size_t)row * S_DIM + h * 32;
#pragma unroll
        for (int c8 = 0; c8 < 4; ++c8) {
            half8 ql, qh, kl, kh;
#pragma unroll
            for (int e = 0; e < 8; ++e) {
                const int j = h * 32 + c8 * 8 + e;
                float b1 = (float)sl.tr[rl][j];
                float b2 = (float)sl.tr[rl][j + 64];
                float c = cT[c8 * 8 + e], s = sT[c8 * 8 + e];
                float x1 = b1 * gamma[j] + beta[j];
                float x2 = b2 * gamma[j + 64] + beta[j + 64];
                ql[e] = (f16)(x1 * c - x2 * s);
                qh[e] = (f16)(x2 * c + x1 * s);
                float y1 = b1 * gamma[128 + j] + beta[128 + j];
                float y2 = b2 * gamma[192 + j] + beta[192 + j];
                kl[e] = (f16)(y1 * c - y2 * s);
                kh[e] = (f16)(y2 * c + y1 * s);
            }
            *(half8*)(qp + c8 * 8) = ql;
            *(half8*)(qp + 64 + c8 * 8) = qh;
            *(half8*)(kp + c8 * 8) = kl;
            *(half8*)(kp + 64 + c8 * 8) = kh;
        }
    }
}

// ---------------- GEMM 2: two kern chunks per launch (z = b + 4*half) ------
__global__ __launch_bounds__(256) void k_mm_qk(const f16* __restrict__ q,
                                               const f16* __restrict__ k,
                                               f16* __restrict__ kc0,
                                               f16* __restrict__ kc1, int pair) {
    __shared__ f16 stage[256 * 64];
    const int b = blockIdx.z & 3;
    const int half = blockIdx.z >> 2;
    f16* kern = half ? kc1 : kc0;
    const int mc = pair * 2 + half;
    const int m0 = blockIdx.y * 128, n0 = blockIdx.x * 128;
    f32x4 acc[4][4];
#pragma unroll
    for (int i = 0; i < 4; ++i)
#pragma unroll
        for (int j = 0; j < 4; ++j) acc[i][j] = (f32x4){0.f, 0.f, 0.f, 0.f};
    const char* Ab = (const char*)(q + (size_t)(b * L_DIM + mc * 1024 + m0) * S_DIM);
    const char* Bb = (const char*)(k + (size_t)(b * L_DIM + n0) * S_DIM);
    mfma_core<4, 4>(Ab, S_DIM * 2, Bb, S_DIM * 2, S_DIM, stage, acc);
    const int lane = threadIdx.x & 63, wv = threadIdx.x >> 6;
    const int wr = wv >> 1, wc = wv & 1;
#pragma unroll
    for (int mt = 0; mt < 4; ++mt)
#pragma unroll
        for (int nt = 0; nt < 4; ++nt)
#pragma unroll
            for (int r = 0; r < 4; ++r) {
                int ml = wr * 64 + mt * 16 + (lane >> 4) * 4 + r;
                int nl = wc * 64 + nt * 16 + (lane & 15);
                float t = fmaxf(acc[mt][nt][r] * INV_SQRT_S, 0.f);
                t = fminf(t, 240.f);  // fp16-range guard (inert on real data)
                kern[(size_t)(b * 1024 + m0 + ml) * L_DIM + (n0 + nl)] = (f16)(t * t);
            }
}

// ---------------- GEMM 3: aub = u ⊙ (kern @ v), r8 dbuf core ---------------
// blockIdx.x = m-tile so id%8 == m-tile -> kern A-panel XCD-local.
__global__ __launch_bounds__(256) void k_mm_av(const f16* __restrict__ kc0,
                                               const f16* __restrict__ kc1,
                                               const f16* __restrict__ vT,
                                               const f16* __restrict__ u,
                                               f16* __restrict__ aub, int pair) {
    __shared__ union {
        struct { char s0[32768]; char s1[32768]; } st;
        f16 tr[128][136];
    } sl;
    const int b = blockIdx.z & 3;
    const int half = blockIdx.z >> 2;
    const f16* kern = half ? kc1 : kc0;
    const int mc = pair * 2 + half;
    const int m0 = blockIdx.x * 128, n0 = blockIdx.y * 128;  // x <-> m (XCD locality)
    f32x4 acc[4][4];
#pragma unroll
    for (int i = 0; i < 4; ++i)
#pragma unroll
        for (int j = 0; j < 4; ++j) acc[i][j] = (f32x4){0.f, 0.f, 0.f, 0.f};
    const char* Ab = (const char*)(kern + (size_t)(b * 1024 + m0) * L_DIM);
    const char* Bb = (const char*)(vT + ((size_t)b * E_DIM + n0) * L_DIM);
    mfma_core_db<4, 4>(Ab, L_DIM * 2, Bb, L_DIM * 2, L_DIM, sl.st.s0, sl.st.s1, acc);
    const int lane = threadIdx.x & 63, wv = threadIdx.x >> 6;
    const int wr = wv >> 1, wc = wv & 1;
#pragma unroll
    for (int nt = 0; nt < 4; ++nt) {
        int nl = wc * 64 + nt * 16 + (lane & 15);
#pragma unroll
        for (int mt = 0; mt < 4; ++mt)
#pragma unroll
            for (int r = 0; r < 4; ++r) {
                int ml = wr * 64 + mt * 16 + (lane >> 4) * 4 + r;
                sl.tr[ml][nl] = (f16)acc[mt][nt][r];
            }
    }
    __syncthreads();
    int rl = threadIdx.x >> 1, h = threadIdx.x & 1;
    size_t mg = (size_t)b * L_DIM + (size_t)mc * 1024 + m0 + rl;
    const f16* up = u + mg * E_DIM + n0 + h * 64;
    f16* ap = aub + mg * E_DIM + n0 + h * 64;
#pragma unroll
    for (int i = 0; i < 8; ++i) {
        half8 s8 = *(const half8*)&sl.tr[rl][h * 64 + i * 8];
        half8 u8 = *(const half8*)(up + i * 8);
        half8 o8;
#pragma unroll
        for (int j = 0; j < 8; ++j) {
            float val = (float)s8[j] * (float)u8[j];
            val = fminf(fmaxf(val, -60000.f), 60000.f);  // fp16-range guard
            o8[j] = (f16)val;
        }
        *(half8*)(ap + i * 8) = o8;
    }
}

// ---------------- GEMM 4: out = aub @ o_w^T + o_b + x (r8 dbuf) ------------
__global__ __launch_bounds__(256) void k_mm_out(const f16* __restrict__ aub,
                                                const f16* __restrict__ wo,
                                                const float* __restrict__ ob,
                                                const float* __restrict__ x,
                                                float* __restrict__ out) {
    __shared__ char s0[32768];
    __shared__ char s1[32768];
    const int m0 = blockIdx.y * 128, n0 = blockIdx.x * 128;
    f32x4 acc[4][4];
#pragma unroll
    for (int i = 0; i < 4; ++i)
#pragma unroll
        for (int j = 0; j < 4; ++j) acc[i][j] = (f32x4){0.f, 0.f, 0.f, 0.f};
    mfma_core_db<4, 4>((const char*)(aub + (size_t)m0 * E_DIM), E_DIM * 2,
                       (const char*)(wo + (size_t)n0 * E_DIM), E_DIM * 2,
                       E_DIM, s0, s1, acc);
    const int lane = threadIdx.x & 63, wv = threadIdx.x >> 6;
    const int wr = wv >> 1, wc = wv & 1;
#pragma unroll
    for (int nt = 0; nt < 4; ++nt) {
        int nl = wc * 64 + nt * 16 + (lane & 15);
        float obv = ob[n0 + nl];
#pragma unroll
        for (int mt = 0; mt < 4; ++mt)
#pragma unroll
            for (int r = 0; r < 4; ++r) {
                int ml = wr * 64 + mt * 16 + (lane >> 4) * 4 + r;
                size_t m = m0 + ml;
                size_t n = n0 + nl;
                out[m * H_DIM + n] = acc[mt][nt][r] + obv + x[m * H_DIM + n];
            }
    }
}

extern "C" void kernel_launch(void* const* d_in, const int* in_sizes, int n_in,
                              void* d_out, int out_size, void* d_ws, size_t ws_size,
                              hipStream_t stream) {
    const float* x     = (const float*)d_in[0];
    const float* ln_w  = (const float*)d_in[1];
    const float* ln_b  = (const float*)d_in[2];
    const float* uv_w  = (const float*)d_in[3];
    const float* uv_b  = (const float*)d_in[4];
    const float* gamma = (const float*)d_in[5];
    const float* beta  = (const float*)d_in[6];
    const float* o_w   = (const float*)d_in[7];
    const float* o_b   = (const float*)d_in[8];
    float* out = (float*)d_out;
    char* ws = (char*)d_ws;

    f16* wuv  = (f16*)(ws + OFF_WUV);
    f16* wo   = (f16*)(ws + OFF_WO);
    f16* u    = (f16*)(ws + OFF_U);
    f16* vT   = (f16*)(ws + OFF_VT);
    f16* aub  = (f16*)(ws + OFF_AUB);
    f16* q    = (f16*)(ws + OFF_Q);
    f16* k    = (f16*)(ws + OFF_K);
    f16* kc0  = (f16*)(ws + OFF_KC0);
    f16* kc1  = (f16*)(ws + OFF_KC1);
    f16* xn   = (f16*)(ws + OFF_XN);
    float* cosT = (float*)(ws + OFF_COS);
    float* sinT = (float*)(ws + OFF_SIN);

    k_tables<<<1024, 256, 0, stream>>>(cosT, sinT);
    k_cvt_w<<<1600, 256, 0, stream>>>(uv_w, o_w, wuv, wo);
    k_xn<<<4096, 256, 0, stream>>>(x, ln_w, ln_b, xn);
    k_mm_uv<<<dim3(17, 128), 256, 0, stream>>>(xn, wuv, uv_b, u, vT,
                                               gamma, beta, cosT, sinT, q, k);
    // xn (aliased with kc1) is dead from here; qk(half=1) may overwrite it.
    for (int pair = 0; pair < 2; ++pair) {
        k_mm_qk<<<dim3(32, 8, 8), 256, 0, stream>>>(q, k, kc0, kc1, pair);
        k_mm_av<<<dim3(8, 8, 8), 256, 0, stream>>>(kc0, kc1, vT, u, aub, pair);
    }
    k_mm_out<<<dim3(4, 128), 256, 0, stream>>>(aub, wo, o_b, x, out);
}

// Round 13
// 328.751 us; speedup vs baseline: 1.1055x; 1.1055x over previous
//
#include <hip/hip_runtime.h>
#include <math.h>

// Problem constants
#define L_DIM 4096
#define B_DIM 4
#define H_DIM 512
#define E_DIM 1024
#define S_DIM 128
#define HALF  64
#define N_ROWS 16384
#define NUV   2176
#define LN_EPS 1e-5f
#define INV_SQRT_S 0.08838834764831845f

typedef _Float16 f16;
typedef __attribute__((ext_vector_type(8))) _Float16 half8;
typedef __attribute__((ext_vector_type(4))) _Float16 half4;
typedef __attribute__((ext_vector_type(4))) float f32x4;

// fast silu: v_exp_f32 + v_rcp_f32 — safe only with VGPR pinned (LB 256,4)
__device__ __forceinline__ float fast_silu(float s) {
    return s * __builtin_amdgcn_rcpf(1.f + __expf(-s));
}

// ---------------- workspace byte offsets ----------------
// kc1 aliases ONLY xn (dead after uv, both sides touched via
// global_load_lds / stores only). cos/sin/braw fully de-aliased.
#define OFF_WUV  ((size_t)0)                        // f16 [2176][512]   2.2 MB
#define OFF_WO   (OFF_WUV + 2228224)                // f16 [512][1024]   1 MB
#define OFF_U    (OFF_WO + 1048576)                 // f16 [16384][1024] 32 MB
#define OFF_VT   (OFF_U + 33554432)                 // f16 [4][1024][4096] 32 MB
#define OFF_AUB  (OFF_VT + 33554432)                // f16 [16384][1024] 32 MB
#define OFF_Q    (OFF_AUB + 33554432)               // f16 [16384][128]  4 MB
#define OFF_K    (OFF_Q + 4194304)                  // f16 [16384][128]  4 MB
#define OFF_KC0  (OFF_K + 4194304)                  // f16 [4][1024][4096] 32 MB
#define OFF_KC1  (OFF_KC0 + 33554432)               // f16 [4][1024][4096] 32 MB
#define OFF_XN   OFF_KC1                            // f16 [16384][512] (aliased)
#define OFF_COS  (OFF_KC1 + 33554432)               // f32 [4096][64]   1 MB
#define OFF_SIN  (OFF_COS + 1048576)                // f32 [4096][64]   1 MB
#define OFF_BR   (OFF_SIN + 1048576)                // f32 [16384][128] 8 MB
// end = OFF_BR + 8MB = 189,923,328 B = 181.1 MiB (< proven 186.1)

// ---------------- RoPE cos/sin tables ----------------
__global__ void k_tables(float* __restrict__ cosT, float* __restrict__ sinT) {
    int idx = blockIdx.x * 256 + threadIdx.x;
    if (idx >= L_DIM * HALF) return;
    int pos = idx >> 6;
    int j = idx & 63;
    float invf = (float)pow(10000.0, (double)j / 64.0);
    float angf = (float)pos * invf;
    double ang = (double)angf;
    cosT[idx] = (float)cos(ang);
    sinT[idx] = (float)sin(ang);
}

// ---------------- fused LN stats + apply + f16 convert (1 wave / row) ------
__global__ __launch_bounds__(256) void k_xn(const float* __restrict__ x,
                                            const float* __restrict__ lnw,
                                            const float* __restrict__ lnb,
                                            f16* __restrict__ xn) {
    int row = blockIdx.x * 4 + (threadIdx.x >> 6);
    int lane = threadIdx.x & 63;
    const float4* xr = (const float4*)(x + (size_t)row * H_DIM);
    float4 a = xr[lane * 2], b = xr[lane * 2 + 1];
    float s = a.x + a.y + a.z + a.w + b.x + b.y + b.z + b.w;
    float s2 = a.x * a.x + a.y * a.y + a.z * a.z + a.w * a.w
             + b.x * b.x + b.y * b.y + b.z * b.z + b.w * b.w;
#pragma unroll
    for (int off = 32; off > 0; off >>= 1) {
        s  += __shfl_xor(s, off);
        s2 += __shfl_xor(s2, off);
    }
    float m = s / (float)H_DIM;
    float var = s2 / (float)H_DIM - m * m;
    float r = rsqrtf(var + LN_EPS);
    const float4* wr4 = (const float4*)lnw;
    const float4* br4 = (const float4*)lnb;
    float4 wa = wr4[lane * 2], wb = wr4[lane * 2 + 1];
    float4 ba = br4[lane * 2], bb = br4[lane * 2 + 1];
    half8 o;
    o[0] = (f16)((a.x - m) * r * wa.x + ba.x);
    o[1] = (f16)((a.y - m) * r * wa.y + ba.y);
    o[2] = (f16)((a.z - m) * r * wa.z + ba.z);
    o[3] = (f16)((a.w - m) * r * wa.w + ba.w);
    o[4] = (f16)((b.x - m) * r * wb.x + bb.x);
    o[5] = (f16)((b.y - m) * r * wb.y + bb.y);
    o[6] = (f16)((b.z - m) * r * wb.z + bb.z);
    o[7] = (f16)((b.w - m) * r * wb.w + bb.w);
    *(half8*)(xn + (size_t)row * H_DIM + lane * 8) = o;
}

// ---------------- weight conversion (uv_w then o_w) ----------------
__global__ __launch_bounds__(256) void k_cvt_w(const float* __restrict__ uvw,
                                               const float* __restrict__ ow,
                                               f16* __restrict__ duv,
                                               f16* __restrict__ dow) {
    int gid = blockIdx.x * 256 + threadIdx.x;
    int i4 = gid << 2;
    const float* src;
    f16* dst;
    int off;
    if (i4 < NUV * H_DIM) { src = uvw; dst = duv; off = i4; }
    else { src = ow; dst = dow; off = i4 - NUV * H_DIM; }
    float4 v = *(const float4*)(src + off);
    half4 o = {(f16)v.x, (f16)v.y, (f16)v.z, (f16)v.w};
    *(half4*)(dst + off) = o;
}

// ---------------- MFMA cores: C = A · B^T (both K-major f16) ----------------
__device__ __forceinline__ void gload16(const void* g, void* l) {
    __builtin_amdgcn_global_load_lds(
        (const __attribute__((address_space(1))) unsigned int*)g,
        (__attribute__((address_space(3))) unsigned int*)l, 16, 0, 0);
}

// Single-buffer core (hoisted addressing) — for uv (4 blocks/CU) & qk.
template <int MT, int NT>
__device__ __forceinline__ void mfma_core(const char* Ab, int lda_b,
                                          const char* Bb, int ldb_b,
                                          int K, f16* lds, f32x4 acc[MT][NT]) {
    constexpr int BM = 32 * MT, BN = 32 * NT;
    constexpr int ISS = (BM + BN) / 32;
    constexpr int ASLOTS = (BM * 128) / 1024;
    const int tid = threadIdx.x;
    const int lane = tid & 63;
    const int wv = tid >> 6;
    const int wr = wv >> 1, wc = wv & 1;
    char* ldsc = (char*)lds;

    const char* sb[ISS];
    unsigned voff[ISS];
#pragma unroll
    for (int i = 0; i < ISS; ++i) {
        const int slot = wv * ISS + i;
        const int ell = (slot << 10) + (lane << 4);
        if (slot < ASLOTS) {
            int row = ell >> 7, kb = ell & 127;
            sb[i] = Ab;
            voff[i] = (unsigned)row * (unsigned)lda_b + (unsigned)(kb ^ ((row & 7) << 4));
        } else {
            const int e2 = ell - BM * 128;
            int row = e2 >> 7, kb = e2 & 127;
            sb[i] = Bb;
            voff[i] = (unsigned)row * (unsigned)ldb_b + (unsigned)(kb ^ ((row & 7) << 4));
        }
    }
    unsigned aoff[MT], boff[NT];
#pragma unroll
    for (int mt = 0; mt < MT; ++mt) {
        int row = wr * (MT * 16) + mt * 16 + (lane & 15);
        unsigned byt = (unsigned)((row << 7) + ((lane >> 4) << 4));
        aoff[mt] = byt ^ (unsigned)((row & 7) << 4);
    }
#pragma unroll
    for (int nt = 0; nt < NT; ++nt) {
        int row = wc * (NT * 16) + nt * 16 + (lane & 15);
        unsigned byt = (unsigned)((row << 7) + ((lane >> 4) << 4));
        boff[nt] = (byt ^ (unsigned)((row & 7) << 4)) + (unsigned)(BM * 128);
    }

    for (int k0 = 0; k0 < K; k0 += 64) {
        const unsigned kbyte = (unsigned)(k0 << 1);
#pragma unroll
        for (int i = 0; i < ISS; ++i)
            gload16(sb[i] + voff[i] + kbyte, ldsc + ((wv * ISS + i) << 10));
        __syncthreads();
#pragma unroll
        for (int ks = 0; ks < 2; ++ks) {
            half8 af[MT], bf[NT];
#pragma unroll
            for (int mt = 0; mt < MT; ++mt)
                af[mt] = *(const half8*)(ldsc + (aoff[mt] ^ (unsigned)(ks << 6)));
#pragma unroll
            for (int nt = 0; nt < NT; ++nt)
                bf[nt] = *(const half8*)(ldsc + (boff[nt] ^ (unsigned)(ks << 6)));
#pragma unroll
            for (int mt = 0; mt < MT; ++mt)
#pragma unroll
                for (int nt = 0; nt < NT; ++nt)
                    acc[mt][nt] = __builtin_amdgcn_mfma_f32_16x16x32_f16(af[mt], bf[nt], acc[mt][nt], 0, 0, 0);
        }
        __syncthreads();
    }
}

// 2-phase dbuf core (r8-proven, A+B staged) — for av & out.
template <int MT, int NT>
__device__ __forceinline__ void mfma_core_db(const char* Ab, int lda_b,
                                             const char* Bb, int ldb_b,
                                             int K, char* l0, char* l1,
                                             f32x4 acc[MT][NT]) {
    constexpr int BM = 32 * MT, BN = 32 * NT;
    constexpr int ISS = (BM + BN) / 32;
    constexpr int ASLOTS = (BM * 128) / 1024;
    const int tid = threadIdx.x;
    const int lane = tid & 63;
    const int wv = tid >> 6;
    const int wr = wv >> 1, wc = wv & 1;

    const char* sb[ISS];
    unsigned voff[ISS];
#pragma unroll
    for (int i = 0; i < ISS; ++i) {
        const int slot = wv * ISS + i;
        const int ell = (slot << 10) + (lane << 4);
        if (slot < ASLOTS) {
            int row = ell >> 7, kb = ell & 127;
            sb[i] = Ab;
            voff[i] = (unsigned)row * (unsigned)lda_b + (unsigned)(kb ^ ((row & 7) << 4));
        } else {
            const int e2 = ell - BM * 128;
            int row = e2 >> 7, kb = e2 & 127;
            sb[i] = Bb;
            voff[i] = (unsigned)row * (unsigned)ldb_b + (unsigned)(kb ^ ((row & 7) << 4));
        }
    }
    unsigned aoff[MT], boff[NT];
#pragma unroll
    for (int mt = 0; mt < MT; ++mt) {
        int row = wr * (MT * 16) + mt * 16 + (lane & 15);
        unsigned byt = (unsigned)((row << 7) + ((lane >> 4) << 4));
        aoff[mt] = byt ^ (unsigned)((row & 7) << 4);
    }
#pragma unroll
    for (int nt = 0; nt < NT; ++nt) {
        int row = wc * (NT * 16) + nt * 16 + (lane & 15);
        unsigned byt = (unsigned)((row << 7) + ((lane >> 4) << 4));
        boff[nt] = (byt ^ (unsigned)((row & 7) << 4)) + (unsigned)(BM * 128);
    }

    auto stage = [&](char* dst, unsigned kbyte) {
#pragma unroll
        for (int i = 0; i < ISS; ++i)
            gload16(sb[i] + voff[i] + kbyte, dst + ((wv * ISS + i) << 10));
    };
    auto compute = [&](const char* src) {
#pragma unroll
        for (int ks = 0; ks < 2; ++ks) {
            half8 af[MT], bf[NT];
#pragma unroll
            for (int mt = 0; mt < MT; ++mt)
                af[mt] = *(const half8*)(src + (aoff[mt] ^ (unsigned)(ks << 6)));
#pragma unroll
            for (int nt = 0; nt < NT; ++nt)
                bf[nt] = *(const half8*)(src + (boff[nt] ^ (unsigned)(ks << 6)));
#pragma unroll
            for (int mt = 0; mt < MT; ++mt)
#pragma unroll
                for (int nt = 0; nt < NT; ++nt)
                    acc[mt][nt] = __builtin_amdgcn_mfma_f32_16x16x32_f16(af[mt], bf[nt], acc[mt][nt], 0, 0, 0);
        }
    };

    const int nst = K / 64;  // even
    stage(l0, 0u);
    __syncthreads();
    for (int t = 0; t < nst; t += 2) {
        stage(l1, (unsigned)(t + 1) * 128u);   // prefetch t+1 while computing t
        compute(l0);
        __syncthreads();
        if (t + 2 < nst) stage(l0, (unsigned)(t + 2) * 128u);
        compute(l1);
        __syncthreads();
    }
}

// ---------------- GEMM 1: silu(LN(x)@uv_w^T + b) -> u | vT | braw ----------
__global__ __launch_bounds__(256, 4) void k_mm_uv(const f16* __restrict__ xn,
                                                  const f16* __restrict__ wuv,
                                                  const float* __restrict__ bias,
                                                  f16* __restrict__ u,
                                                  f16* __restrict__ vT,
                                                  float* __restrict__ braw) {
    __shared__ union {
        f16 stage[256 * 64];
        f16 tr[128][136];
    } sl;
    const int m0 = blockIdx.y * 128, n0 = blockIdx.x * 128;
    f32x4 acc[4][4];
#pragma unroll
    for (int i = 0; i < 4; ++i)
#pragma unroll
        for (int j = 0; j < 4; ++j) acc[i][j] = (f32x4){0.f, 0.f, 0.f, 0.f};
    mfma_core<4, 4>((const char*)(xn + (size_t)m0 * H_DIM), H_DIM * 2,
                    (const char*)(wuv + (size_t)n0 * H_DIM), H_DIM * 2,
                    H_DIM, sl.stage, acc);
    const int lane = threadIdx.x & 63, wv = threadIdx.x >> 6;
    const int wr = wv >> 1, wc = wv & 1;
    if (n0 < E_DIM) {  // u region -> LDS tile -> coalesced wide stores
#pragma unroll
        for (int nt = 0; nt < 4; ++nt) {
            int nl = wc * 64 + nt * 16 + (lane & 15);
            float bs = bias[n0 + nl];
#pragma unroll
            for (int mt = 0; mt < 4; ++mt)
#pragma unroll
                for (int r = 0; r < 4; ++r) {
                    int ml = wr * 64 + mt * 16 + (lane >> 4) * 4 + r;
                    sl.tr[ml][nl] = (f16)fast_silu(acc[mt][nt][r] + bs);
                }
        }
        __syncthreads();
        int rl = threadIdx.x >> 1, h = threadIdx.x & 1;
        f16* dst = u + (size_t)(m0 + rl) * E_DIM + n0 + h * 64;
#pragma unroll
        for (int i = 0; i < 8; ++i)
            *(uint4*)(dst + i * 8) = *(const uint4*)&sl.tr[rl][h * 64 + i * 8];
    } else if (n0 < 2 * E_DIM) {  // v region -> transposed store via LDS
#pragma unroll
        for (int nt = 0; nt < 4; ++nt) {
            int nl = wc * 64 + nt * 16 + (lane & 15);
            float bs = bias[n0 + nl];
#pragma unroll
            for (int mt = 0; mt < 4; ++mt)
#pragma unroll
                for (int r = 0; r < 4; ++r) {
                    int ml = wr * 64 + mt * 16 + (lane >> 4) * 4 + r;
                    sl.tr[nl][ml] = (f16)fast_silu(acc[mt][nt][r] + bs);
                }
        }
        __syncthreads();
        int rl = threadIdx.x >> 1, h = threadIdx.x & 1;
        int b = m0 >> 12;
        int mloc = m0 & (L_DIM - 1);
        size_t e = (size_t)(n0 - E_DIM) + rl;
        f16* dst = vT + ((size_t)b * E_DIM + e) * L_DIM + mloc + h * 64;
#pragma unroll
        for (int i = 0; i < 8; ++i)
            *(uint4*)(dst + i * 8) = *(const uint4*)&sl.tr[rl][h * 64 + i * 8];
    } else {  // braw region (f32, 1/17 of blocks)
#pragma unroll
        for (int nt = 0; nt < 4; ++nt) {
            int nl = wc * 64 + nt * 16 + (lane & 15);
            float bs = bias[n0 + nl];
#pragma unroll
            for (int mt = 0; mt < 4; ++mt)
#pragma unroll
                for (int r = 0; r < 4; ++r) {
                    int ml = wr * 64 + mt * 16 + (lane >> 4) * 4 + r;
                    braw[(size_t)(m0 + ml) * S_DIM + (n0 - 2 * E_DIM + nl)] =
                        fast_silu(acc[mt][nt][r] + bs);
                }
        }
    }
}

// ---------------- gamma/beta + RoPE -> q, k (f16), vectorized --------------
// 16 threads/row, float4 loads, half4 stores. 262144 threads = 1024 blocks.
__global__ __launch_bounds__(256) void k_prep(const float* __restrict__ braw,
                                              const float* __restrict__ gamma,
                                              const float* __restrict__ beta,
                                              const float* __restrict__ cosT,
                                              const float* __restrict__ sinT,
                                              f16* __restrict__ q,
                                              f16* __restrict__ kq) {
    int idx = blockIdx.x * 256 + threadIdx.x;
    int row = idx >> 4;
    int j0 = (idx & 15) << 2;
    int l = row & (L_DIM - 1);
    float4 b1 = *(const float4*)(braw + (size_t)row * S_DIM + j0);
    float4 b2 = *(const float4*)(braw + (size_t)row * S_DIM + j0 + HALF);
    float4 cv = *(const float4*)(cosT + l * HALF + j0);
    float4 sv = *(const float4*)(sinT + l * HALF + j0);
    float4 g1 = *(const float4*)(gamma + j0);
    float4 g2 = *(const float4*)(gamma + j0 + 64);
    float4 g3 = *(const float4*)(gamma + 128 + j0);
    float4 g4 = *(const float4*)(gamma + 192 + j0);
    float4 e1 = *(const float4*)(beta + j0);
    float4 e2 = *(const float4*)(beta + j0 + 64);
    float4 e3 = *(const float4*)(beta + 128 + j0);
    float4 e4 = *(const float4*)(beta + 192 + j0);
    const float* b1a = (const float*)&b1;
    const float* b2a = (const float*)&b2;
    const float* ca = (const float*)&cv;
    const float* sa = (const float*)&sv;
    const float* g1a = (const float*)&g1;
    const float* g2a = (const float*)&g2;
    const float* g3a = (const float*)&g3;
    const float* g4a = (const float*)&g4;
    const float* e1a = (const float*)&e1;
    const float* e2a = (const float*)&e2;
    const float* e3a = (const float*)&e3;
    const float* e4a = (const float*)&e4;
    half4 ql, qh, kl, kh;
#pragma unroll
    for (int e = 0; e < 4; ++e) {
        float x1 = b1a[e] * g1a[e] + e1a[e];
        float x2 = b2a[e] * g2a[e] + e2a[e];
        ql[e] = (f16)(x1 * ca[e] - x2 * sa[e]);
        qh[e] = (f16)(x2 * ca[e] + x1 * sa[e]);
        float y1 = b1a[e] * g3a[e] + e3a[e];
        float y2 = b2a[e] * g4a[e] + e4a[e];
        kl[e] = (f16)(y1 * ca[e] - y2 * sa[e]);
        kh[e] = (f16)(y2 * ca[e] + y1 * sa[e]);
    }
    *(half4*)(q + (size_t)row * S_DIM + j0) = ql;
    *(half4*)(q + (size_t)row * S_DIM + j0 + HALF) = qh;
    *(half4*)(kq + (size_t)row * S_DIM + j0) = kl;
    *(half4*)(kq + (size_t)row * S_DIM + j0 + HALF) = kh;
}

// ---------------- GEMM 2: two kern chunks per launch (z = b + 4*half) ------
__global__ __launch_bounds__(256) void k_mm_qk(const f16* __restrict__ q,
                                               const f16* __restrict__ k,
                                               f16* __restrict__ kc0,
                                               f16* __restrict__ kc1, int pair) {
    __shared__ f16 stage[256 * 64];
    const int b = blockIdx.z & 3;
    const int half = blockIdx.z >> 2;
    f16* kern = half ? kc1 : kc0;
    const int mc = pair * 2 + half;
    const int m0 = blockIdx.y * 128, n0 = blockIdx.x * 128;
    f32x4 acc[4][4];
#pragma unroll
    for (int i = 0; i < 4; ++i)
#pragma unroll
        for (int j = 0; j < 4; ++j) acc[i][j] = (f32x4){0.f, 0.f, 0.f, 0.f};
    const char* Ab = (const char*)(q + (size_t)(b * L_DIM + mc * 1024 + m0) * S_DIM);
    const char* Bb = (const char*)(k + (size_t)(b * L_DIM + n0) * S_DIM);
    mfma_core<4, 4>(Ab, S_DIM * 2, Bb, S_DIM * 2, S_DIM, stage, acc);
    const int lane = threadIdx.x & 63, wv = threadIdx.x >> 6;
    const int wr = wv >> 1, wc = wv & 1;
#pragma unroll
    for (int mt = 0; mt < 4; ++mt)
#pragma unroll
        for (int nt = 0; nt < 4; ++nt)
#pragma unroll
            for (int r = 0; r < 4; ++r) {
                int ml = wr * 64 + mt * 16 + (lane >> 4) * 4 + r;
                int nl = wc * 64 + nt * 16 + (lane & 15);
                float t = fmaxf(acc[mt][nt][r] * INV_SQRT_S, 0.f);
                t = fminf(t, 240.f);  // fp16-range guard (inert on real data)
                kern[(size_t)(b * 1024 + m0 + ml) * L_DIM + (n0 + nl)] = (f16)(t * t);
            }
}

// ---------------- GEMM 3: aub = u ⊙ (kern @ v), r8 dbuf core ---------------
// blockIdx.x = m-tile so id%8 == m-tile -> kern A-panel XCD-local.
__global__ __launch_bounds__(256) void k_mm_av(const f16* __restrict__ kc0,
                                               const f16* __restrict__ kc1,
                                               const f16* __restrict__ vT,
                                               const f16* __restrict__ u,
                                               f16* __restrict__ aub, int pair) {
    __shared__ union {
        struct { char s0[32768]; char s1[32768]; } st;
        f16 tr[128][136];
    } sl;
    const int b = blockIdx.z & 3;
    const int half = blockIdx.z >> 2;
    const f16* kern = half ? kc1 : kc0;
    const int mc = pair * 2 + half;
    const int m0 = blockIdx.x * 128, n0 = blockIdx.y * 128;  // x <-> m (XCD locality)
    f32x4 acc[4][4];
#pragma unroll
    for (int i = 0; i < 4; ++i)
#pragma unroll
        for (int j = 0; j < 4; ++j) acc[i][j] = (f32x4){0.f, 0.f, 0.f, 0.f};
    const char* Ab = (const char*)(kern + (size_t)(b * 1024 + m0) * L_DIM);
    const char* Bb = (const char*)(vT + ((size_t)b * E_DIM + n0) * L_DIM);
    mfma_core_db<4, 4>(Ab, L_DIM * 2, Bb, L_DIM * 2, L_DIM, sl.st.s0, sl.st.s1, acc);
    const int lane = threadIdx.x & 63, wv = threadIdx.x >> 6;
    const int wr = wv >> 1, wc = wv & 1;
#pragma unroll
    for (int nt = 0; nt < 4; ++nt) {
        int nl = wc * 64 + nt * 16 + (lane & 15);
#pragma unroll
        for (int mt = 0; mt < 4; ++mt)
#pragma unroll
            for (int r = 0; r < 4; ++r) {
                int ml = wr * 64 + mt * 16 + (lane >> 4) * 4 + r;
                sl.tr[ml][nl] = (f16)acc[mt][nt][r];
            }
    }
    __syncthreads();
    int rl = threadIdx.x >> 1, h = threadIdx.x & 1;
    size_t mg = (size_t)b * L_DIM + (size_t)mc * 1024 + m0 + rl;
    const f16* up = u + mg * E_DIM + n0 + h * 64;
    f16* ap = aub + mg * E_DIM + n0 + h * 64;
#pragma unroll
    for (int i = 0; i < 8; ++i) {
        half8 s8 = *(const half8*)&sl.tr[rl][h * 64 + i * 8];
        half8 u8 = *(const half8*)(up + i * 8);
        half8 o8;
#pragma unroll
        for (int j = 0; j < 8; ++j) {
            float val = (float)s8[j] * (float)u8[j];
            val = fminf(fmaxf(val, -60000.f), 60000.f);  // fp16-range guard
            o8[j] = (f16)val;
        }
        *(half8*)(ap + i * 8) = o8;
    }
}

// ---------------- GEMM 4: out = aub @ o_w^T + o_b + x (r8 dbuf) ------------
__global__ __launch_bounds__(256) void k_mm_out(const f16* __restrict__ aub,
                                                const f16* __restrict__ wo,
                                                const float* __restrict__ ob,
                                                const float* __restrict__ x,
                                                float* __restrict__ out) {
    __shared__ char s0[32768];
    __shared__ char s1[32768];
    const int m0 = blockIdx.y * 128, n0 = blockIdx.x * 128;
    f32x4 acc[4][4];
#pragma unroll
    for (int i = 0; i < 4; ++i)
#pragma unroll
        for (int j = 0; j < 4; ++j) acc[i][j] = (f32x4){0.f, 0.f, 0.f, 0.f};
    mfma_core_db<4, 4>((const char*)(aub + (size_t)m0 * E_DIM), E_DIM * 2,
                       (const char*)(wo + (size_t)n0 * E_DIM), E_DIM * 2,
                       E_DIM, s0, s1, acc);
    const int lane = threadIdx.x & 63, wv = threadIdx.x >> 6;
    const int wr = wv >> 1, wc = wv & 1;
#pragma unroll
    for (int nt = 0; nt < 4; ++nt) {
        int nl = wc * 64 + nt * 16 + (lane & 15);
        float obv = ob[n0 + nl];
#pragma unroll
        for (int mt = 0; mt < 4; ++mt)
#pragma unroll
            for (int r = 0; r < 4; ++r) {
                int ml = wr * 64 + mt * 16 + (lane >> 4) * 4 + r;
                size_t m = m0 + ml;
                size_t n = n0 + nl;
                out[m * H_DIM + n] = acc[mt][nt][r] + obv + x[m * H_DIM + n];
            }
    }
}

extern "C" void kernel_launch(void* const* d_in, const int* in_sizes, int n_in,
                              void* d_out, int out_size, void* d_ws, size_t ws_size,
                              hipStream_t stream) {
    const float* x     = (const float*)d_in[0];
    const float* ln_w  = (const float*)d_in[1];
    const float* ln_b  = (const float*)d_in[2];
    const float* uv_w  = (const float*)d_in[3];
    const float* uv_b  = (const float*)d_in[4];
    const float* gamma = (const float*)d_in[5];
    const float* beta  = (const float*)d_in[6];
    const float* o_w   = (const float*)d_in[7];
    const float* o_b   = (const float*)d_in[8];
    float* out = (float*)d_out;
    char* ws = (char*)d_ws;

    f16* wuv  = (f16*)(ws + OFF_WUV);
    f16* wo   = (f16*)(ws + OFF_WO);
    f16* u    = (f16*)(ws + OFF_U);
    f16* vT   = (f16*)(ws + OFF_VT);
    f16* aub  = (f16*)(ws + OFF_AUB);
    f16* q    = (f16*)(ws + OFF_Q);
    f16* k    = (f16*)(ws + OFF_K);
    f16* kc0  = (f16*)(ws + OFF_KC0);
    f16* kc1  = (f16*)(ws + OFF_KC1);
    f16* xn   = (f16*)(ws + OFF_XN);
    float* cosT = (float*)(ws + OFF_COS);
    float* sinT = (float*)(ws + OFF_SIN);
    float* braw = (float*)(ws + OFF_BR);

    k_tables<<<1024, 256, 0, stream>>>(cosT, sinT);
    k_cvt_w<<<1600, 256, 0, stream>>>(uv_w, o_w, wuv, wo);
    k_xn<<<4096, 256, 0, stream>>>(x, ln_w, ln_b, xn);
    k_mm_uv<<<dim3(17, 128), 256, 0, stream>>>(xn, wuv, uv_b, u, vT, braw);
    k_prep<<<1024, 256, 0, stream>>>(braw, gamma, beta, cosT, sinT, q, k);
    // xn (aliased with kc1) is dead from here; qk(half=1) may overwrite it.
    for (int pair = 0; pair < 2; ++pair) {
        k_mm_qk<<<dim3(32, 8, 8), 256, 0, stream>>>(q, k, kc0, kc1, pair);
        k_mm_av<<<dim3(8, 8, 8), 256, 0, stream>>>(kc0, kc1, vT, u, aub, pair);
    }
    k_mm_out<<<dim3(4, 128), 256, 0, stream>>>(aub, wo, o_b, x, out);
}

// Round 14
// 327.434 us; speedup vs baseline: 1.1099x; 1.0040x over previous
//
#include <hip/hip_runtime.h>
#include <math.h>

// Problem constants
#define L_DIM 4096
#define B_DIM 4
#define H_DIM 512
#define E_DIM 1024
#define S_DIM 128
#define HALF  64
#define N_ROWS 16384
#define NUV   2176
#define LN_EPS 1e-5f
#define INV_SQRT_S 0.08838834764831845f

typedef _Float16 f16;
typedef __attribute__((ext_vector_type(8))) _Float16 half8;
typedef __attribute__((ext_vector_type(4))) _Float16 half4;
typedef __attribute__((ext_vector_type(4))) float f32x4;

// fast silu: v_exp_f32 + v_rcp_f32 — safe only with VGPR pinned (LB 256,4)
__device__ __forceinline__ float fast_silu(float s) {
    return s * __builtin_amdgcn_rcpf(1.f + __expf(-s));
}

// ---------------- workspace byte offsets ----------------
// kc1 aliases ONLY xn (dead after uv, both sides touched via
// global_load_lds / stores only). cos/sin/braw fully de-aliased.
#define OFF_WUV  ((size_t)0)                        // f16 [2176][512]   2.2 MB
#define OFF_WO   (OFF_WUV + 2228224)                // f16 [512][1024]   1 MB
#define OFF_U    (OFF_WO + 1048576)                 // f16 [16384][1024] 32 MB
#define OFF_VT   (OFF_U + 33554432)                 // f16 [4][1024][4096] 32 MB
#define OFF_AUB  (OFF_VT + 33554432)                // f16 [16384][1024] 32 MB
#define OFF_Q    (OFF_AUB + 33554432)               // f16 [16384][128]  4 MB
#define OFF_K    (OFF_Q + 4194304)                  // f16 [16384][128]  4 MB
#define OFF_KC0  (OFF_K + 4194304)                  // f16 [4][1024][4096] 32 MB
#define OFF_KC1  (OFF_KC0 + 33554432)               // f16 [4][1024][4096] 32 MB
#define OFF_XN   OFF_KC1                            // f16 [16384][512] (aliased)
#define OFF_COS  (OFF_KC1 + 33554432)               // f32 [4096][64]   1 MB
#define OFF_SIN  (OFF_COS + 1048576)                // f32 [4096][64]   1 MB
#define OFF_BR   (OFF_SIN + 1048576)                // f32 [16384][128] 8 MB
// end = OFF_BR + 8MB = 189,923,328 B = 181.1 MiB (< proven 186.1)

// ---------------- merged prologue: LN+cvt (xn | weights | rope tables) -----
// blocks [0,4096): xn LN (1 wave/row); [4096,5696): weight cvt; [5696,6720): tables
__global__ __launch_bounds__(256) void k_pre(const float* __restrict__ x,
                                             const float* __restrict__ lnw,
                                             const float* __restrict__ lnb,
                                             f16* __restrict__ xn,
                                             const float* __restrict__ uvw,
                                             const float* __restrict__ ow,
                                             f16* __restrict__ duv,
                                             f16* __restrict__ dow,
                                             float* __restrict__ cosT,
                                             float* __restrict__ sinT) {
    const int bid = blockIdx.x;
    if (bid < 4096) {  // ---- LN + f16 convert ----
        int row = bid * 4 + (threadIdx.x >> 6);
        int lane = threadIdx.x & 63;
        const float4* xr = (const float4*)(x + (size_t)row * H_DIM);
        float4 a = xr[lane * 2], b = xr[lane * 2 + 1];
        float s = a.x + a.y + a.z + a.w + b.x + b.y + b.z + b.w;
        float s2 = a.x * a.x + a.y * a.y + a.z * a.z + a.w * a.w
                 + b.x * b.x + b.y * b.y + b.z * b.z + b.w * b.w;
#pragma unroll
        for (int off = 32; off > 0; off >>= 1) {
            s  += __shfl_xor(s, off);
            s2 += __shfl_xor(s2, off);
        }
        float m = s / (float)H_DIM;
        float var = s2 / (float)H_DIM - m * m;
        float r = rsqrtf(var + LN_EPS);
        const float4* wr4 = (const float4*)lnw;
        const float4* br4 = (const float4*)lnb;
        float4 wa = wr4[lane * 2], wb = wr4[lane * 2 + 1];
        float4 ba = br4[lane * 2], bb = br4[lane * 2 + 1];
        half8 o;
        o[0] = (f16)((a.x - m) * r * wa.x + ba.x);
        o[1] = (f16)((a.y - m) * r * wa.y + ba.y);
        o[2] = (f16)((a.z - m) * r * wa.z + ba.z);
        o[3] = (f16)((a.w - m) * r * wa.w + ba.w);
        o[4] = (f16)((b.x - m) * r * wb.x + bb.x);
        o[5] = (f16)((b.y - m) * r * wb.y + bb.y);
        o[6] = (f16)((b.z - m) * r * wb.z + bb.z);
        o[7] = (f16)((b.w - m) * r * wb.w + bb.w);
        *(half8*)(xn + (size_t)row * H_DIM + lane * 8) = o;
    } else if (bid < 5696) {  // ---- weight conversion (uv_w then o_w) ----
        int gid = (bid - 4096) * 256 + threadIdx.x;
        int i4 = gid << 2;
        const float* src;
        f16* dst;
        int off;
        if (i4 < NUV * H_DIM) { src = uvw; dst = duv; off = i4; }
        else { src = ow; dst = dow; off = i4 - NUV * H_DIM; }
        float4 v = *(const float4*)(src + off);
        half4 o = {(f16)v.x, (f16)v.y, (f16)v.z, (f16)v.w};
        *(half4*)(dst + off) = o;
    } else {  // ---- RoPE cos/sin tables ----
        int idx = (bid - 5696) * 256 + threadIdx.x;
        int pos = idx >> 6;
        int j = idx & 63;
        float invf = (float)pow(10000.0, (double)j / 64.0);
        float angf = (float)pos * invf;
        double ang = (double)angf;
        cosT[idx] = (float)cos(ang);
        sinT[idx] = (float)sin(ang);
    }
}

// ---------------- MFMA cores: C = A · B^T (both K-major f16) ----------------
__device__ __forceinline__ void gload16(const void* g, void* l) {
    __builtin_amdgcn_global_load_lds(
        (const __attribute__((address_space(1))) unsigned int*)g,
        (__attribute__((address_space(3))) unsigned int*)l, 16, 0, 0);
}

// Single-buffer core (hoisted addressing) — for uv (4 blocks/CU) & qk.
template <int MT, int NT>
__device__ __forceinline__ void mfma_core(const char* Ab, int lda_b,
                                          const char* Bb, int ldb_b,
                                          int K, f16* lds, f32x4 acc[MT][NT]) {
    constexpr int BM = 32 * MT, BN = 32 * NT;
    constexpr int ISS = (BM + BN) / 32;
    constexpr int ASLOTS = (BM * 128) / 1024;
    const int tid = threadIdx.x;
    const int lane = tid & 63;
    const int wv = tid >> 6;
    const int wr = wv >> 1, wc = wv & 1;
    char* ldsc = (char*)lds;

    const char* sb[ISS];
    unsigned voff[ISS];
#pragma unroll
    for (int i = 0; i < ISS; ++i) {
        const int slot = wv * ISS + i;
        const int ell = (slot << 10) + (lane << 4);
        if (slot < ASLOTS) {
            int row = ell >> 7, kb = ell & 127;
            sb[i] = Ab;
            voff[i] = (unsigned)row * (unsigned)lda_b + (unsigned)(kb ^ ((row & 7) << 4));
        } else {
            const int e2 = ell - BM * 128;
            int row = e2 >> 7, kb = e2 & 127;
            sb[i] = Bb;
            voff[i] = (unsigned)row * (unsigned)ldb_b + (unsigned)(kb ^ ((row & 7) << 4));
        }
    }
    unsigned aoff[MT], boff[NT];
#pragma unroll
    for (int mt = 0; mt < MT; ++mt) {
        int row = wr * (MT * 16) + mt * 16 + (lane & 15);
        unsigned byt = (unsigned)((row << 7) + ((lane >> 4) << 4));
        aoff[mt] = byt ^ (unsigned)((row & 7) << 4);
    }
#pragma unroll
    for (int nt = 0; nt < NT; ++nt) {
        int row = wc * (NT * 16) + nt * 16 + (lane & 15);
        unsigned byt = (unsigned)((row << 7) + ((lane >> 4) << 4));
        boff[nt] = (byt ^ (unsigned)((row & 7) << 4)) + (unsigned)(BM * 128);
    }

    for (int k0 = 0; k0 < K; k0 += 64) {
        const unsigned kbyte = (unsigned)(k0 << 1);
#pragma unroll
        for (int i = 0; i < ISS; ++i)
            gload16(sb[i] + voff[i] + kbyte, ldsc + ((wv * ISS + i) << 10));
        __syncthreads();
#pragma unroll
        for (int ks = 0; ks < 2; ++ks) {
            half8 af[MT], bf[NT];
#pragma unroll
            for (int mt = 0; mt < MT; ++mt)
                af[mt] = *(const half8*)(ldsc + (aoff[mt] ^ (unsigned)(ks << 6)));
#pragma unroll
            for (int nt = 0; nt < NT; ++nt)
                bf[nt] = *(const half8*)(ldsc + (boff[nt] ^ (unsigned)(ks << 6)));
#pragma unroll
            for (int mt = 0; mt < MT; ++mt)
#pragma unroll
                for (int nt = 0; nt < NT; ++nt)
                    acc[mt][nt] = __builtin_amdgcn_mfma_f32_16x16x32_f16(af[mt], bf[nt], acc[mt][nt], 0, 0, 0);
        }
        __syncthreads();
    }
}

// 2-phase dbuf core (r8-proven, A+B staged) — for av & out.
template <int MT, int NT>
__device__ __forceinline__ void mfma_core_db(const char* Ab, int lda_b,
                                             const char* Bb, int ldb_b,
                                             int K, char* l0, char* l1,
                                             f32x4 acc[MT][NT]) {
    constexpr int BM = 32 * MT, BN = 32 * NT;
    constexpr int ISS = (BM + BN) / 32;
    constexpr int ASLOTS = (BM * 128) / 1024;
    const int tid = threadIdx.x;
    const int lane = tid & 63;
    const int wv = tid >> 6;
    const int wr = wv >> 1, wc = wv & 1;

    const char* sb[ISS];
    unsigned voff[ISS];
#pragma unroll
    for (int i = 0; i < ISS; ++i) {
        const int slot = wv * ISS + i;
        const int ell = (slot << 10) + (lane << 4);
        if (slot < ASLOTS) {
            int row = ell >> 7, kb = ell & 127;
            sb[i] = Ab;
            voff[i] = (unsigned)row * (unsigned)lda_b + (unsigned)(kb ^ ((row & 7) << 4));
        } else {
            const int e2 = ell - BM * 128;
            int row = e2 >> 7, kb = e2 & 127;
            sb[i] = Bb;
            voff[i] = (unsigned)row * (unsigned)ldb_b + (unsigned)(kb ^ ((row & 7) << 4));
        }
    }
    unsigned aoff[MT], boff[NT];
#pragma unroll
    for (int mt = 0; mt < MT; ++mt) {
        int row = wr * (MT * 16) + mt * 16 + (lane & 15);
        unsigned byt = (unsigned)((row << 7) + ((lane >> 4) << 4));
        aoff[mt] = byt ^ (unsigned)((row & 7) << 4);
    }
#pragma unroll
    for (int nt = 0; nt < NT; ++nt) {
        int row = wc * (NT * 16) + nt * 16 + (lane & 15);
        unsigned byt = (unsigned)((row << 7) + ((lane >> 4) << 4));
        boff[nt] = (byt ^ (unsigned)((row & 7) << 4)) + (unsigned)(BM * 128);
    }

    auto stage = [&](char* dst, unsigned kbyte) {
#pragma unroll
        for (int i = 0; i < ISS; ++i)
            gload16(sb[i] + voff[i] + kbyte, dst + ((wv * ISS + i) << 10));
    };
    auto compute = [&](const char* src) {
#pragma unroll
        for (int ks = 0; ks < 2; ++ks) {
            half8 af[MT], bf[NT];
#pragma unroll
            for (int mt = 0; mt < MT; ++mt)
                af[mt] = *(const half8*)(src + (aoff[mt] ^ (unsigned)(ks << 6)));
#pragma unroll
            for (int nt = 0; nt < NT; ++nt)
                bf[nt] = *(const half8*)(src + (boff[nt] ^ (unsigned)(ks << 6)));
#pragma unroll
            for (int mt = 0; mt < MT; ++mt)
#pragma unroll
                for (int nt = 0; nt < NT; ++nt)
                    acc[mt][nt] = __builtin_amdgcn_mfma_f32_16x16x32_f16(af[mt], bf[nt], acc[mt][nt], 0, 0, 0);
        }
    };

    const int nst = K / 64;  // even
    stage(l0, 0u);
    __syncthreads();
    for (int t = 0; t < nst; t += 2) {
        stage(l1, (unsigned)(t + 1) * 128u);   // prefetch t+1 while computing t
        compute(l0);
        __syncthreads();
        if (t + 2 < nst) stage(l0, (unsigned)(t + 2) * 128u);
        compute(l1);
        __syncthreads();
    }
}

// ---------------- GEMM 1: silu(LN(x)@uv_w^T + b) -> u | vT | braw ----------
__global__ __launch_bounds__(256, 4) void k_mm_uv(const f16* __restrict__ xn,
                                                  const f16* __restrict__ wuv,
                                                  const float* __restrict__ bias,
                                                  f16* __restrict__ u,
                                                  f16* __restrict__ vT,
                                                  float* __restrict__ braw) {
    __shared__ union {
        f16 stage[256 * 64];
        f16 tr[128][136];
    } sl;
    const int m0 = blockIdx.y * 128, n0 = blockIdx.x * 128;
    f32x4 acc[4][4];
#pragma unroll
    for (int i = 0; i < 4; ++i)
#pragma unroll
        for (int j = 0; j < 4; ++j) acc[i][j] = (f32x4){0.f, 0.f, 0.f, 0.f};
    mfma_core<4, 4>((const char*)(xn + (size_t)m0 * H_DIM), H_DIM * 2,
                    (const char*)(wuv + (size_t)n0 * H_DIM), H_DIM * 2,
                    H_DIM, sl.stage, acc);
    const int lane = threadIdx.x & 63, wv = threadIdx.x >> 6;
    const int wr = wv >> 1, wc = wv & 1;
    if (n0 < E_DIM) {  // u region -> LDS tile -> coalesced wide stores
#pragma unroll
        for (int nt = 0; nt < 4; ++nt) {
            int nl = wc * 64 + nt * 16 + (lane & 15);
            float bs = bias[n0 + nl];
#pragma unroll
            for (int mt = 0; mt < 4; ++mt)
#pragma unroll
                for (int r = 0; r < 4; ++r) {
                    int ml = wr * 64 + mt * 16 + (lane >> 4) * 4 + r;
                    sl.tr[ml][nl] = (f16)fast_silu(acc[mt][nt][r] + bs);
                }
        }
        __syncthreads();
        int rl = threadIdx.x >> 1, h = threadIdx.x & 1;
        f16* dst = u + (size_t)(m0 + rl) * E_DIM + n0 + h * 64;
#pragma unroll
        for (int i = 0; i < 8; ++i)
            *(uint4*)(dst + i * 8) = *(const uint4*)&sl.tr[rl][h * 64 + i * 8];
    } else if (n0 < 2 * E_DIM) {  // v region -> transposed store via LDS
#pragma unroll
        for (int nt = 0; nt < 4; ++nt) {
            int nl = wc * 64 + nt * 16 + (lane & 15);
            float bs = bias[n0 + nl];
#pragma unroll
            for (int mt = 0; mt < 4; ++mt)
#pragma unroll
                for (int r = 0; r < 4; ++r) {
                    int ml = wr * 64 + mt * 16 + (lane >> 4) * 4 + r;
                    sl.tr[nl][ml] = (f16)fast_silu(acc[mt][nt][r] + bs);
                }
        }
        __syncthreads();
        int rl = threadIdx.x >> 1, h = threadIdx.x & 1;
        int b = m0 >> 12;
        int mloc = m0 & (L_DIM - 1);
        size_t e = (size_t)(n0 - E_DIM) + rl;
        f16* dst = vT + ((size_t)b * E_DIM + e) * L_DIM + mloc + h * 64;
#pragma unroll
        for (int i = 0; i < 8; ++i)
            *(uint4*)(dst + i * 8) = *(const uint4*)&sl.tr[rl][h * 64 + i * 8];
    } else {  // braw region (f32, 1/17 of blocks)
#pragma unroll
        for (int nt = 0; nt < 4; ++nt) {
            int nl = wc * 64 + nt * 16 + (lane & 15);
            float bs = bias[n0 + nl];
#pragma unroll
            for (int mt = 0; mt < 4; ++mt)
#pragma unroll
                for (int r = 0; r < 4; ++r) {
                    int ml = wr * 64 + mt * 16 + (lane >> 4) * 4 + r;
                    braw[(size_t)(m0 + ml) * S_DIM + (n0 - 2 * E_DIM + nl)] =
                        fast_silu(acc[mt][nt][r] + bs);
                }
        }
    }
}

// ---------------- gamma/beta + RoPE -> q, k (f16), vectorized --------------
__global__ __launch_bounds__(256) void k_prep(const float* __restrict__ braw,
                                              const float* __restrict__ gamma,
                                              const float* __restrict__ beta,
                                              const float* __restrict__ cosT,
                                              const float* __restrict__ sinT,
                                              f16* __restrict__ q,
                                              f16* __restrict__ kq) {
    int idx = blockIdx.x * 256 + threadIdx.x;
    int row = idx >> 4;
    int j0 = (idx & 15) << 2;
    int l = row & (L_DIM - 1);
    float4 b1 = *(const float4*)(braw + (size_t)row * S_DIM + j0);
    float4 b2 = *(const float4*)(braw + (size_t)row * S_DIM + j0 + HALF);
    float4 cv = *(const float4*)(cosT + l * HALF + j0);
    float4 sv = *(const float4*)(sinT + l * HALF + j0);
    float4 g1 = *(const float4*)(gamma + j0);
    float4 g2 = *(const float4*)(gamma + j0 + 64);
    float4 g3 = *(const float4*)(gamma + 128 + j0);
    float4 g4 = *(const float4*)(gamma + 192 + j0);
    float4 e1 = *(const float4*)(beta + j0);
    float4 e2 = *(const float4*)(beta + j0 + 64);
    float4 e3 = *(const float4*)(beta + 128 + j0);
    float4 e4 = *(const float4*)(beta + 192 + j0);
    const float* b1a = (const float*)&b1;
    const float* b2a = (const float*)&b2;
    const float* ca = (const float*)&cv;
    const float* sa = (const float*)&sv;
    const float* g1a = (const float*)&g1;
    const float* g2a = (const float*)&g2;
    const float* g3a = (const float*)&g3;
    const float* g4a = (const float*)&g4;
    const float* e1a = (const float*)&e1;
    const float* e2a = (const float*)&e2;
    const float* e3a = (const float*)&e3;
    const float* e4a = (const float*)&e4;
    half4 ql, qh, kl, kh;
#pragma unroll
    for (int e = 0; e < 4; ++e) {
        float x1 = b1a[e] * g1a[e] + e1a[e];
        float x2 = b2a[e] * g2a[e] + e2a[e];
        ql[e] = (f16)(x1 * ca[e] - x2 * sa[e]);
        qh[e] = (f16)(x2 * ca[e] + x1 * sa[e]);
        float y1 = b1a[e] * g3a[e] + e3a[e];
        float y2 = b2a[e] * g4a[e] + e4a[e];
        kl[e] = (f16)(y1 * ca[e] - y2 * sa[e]);
        kh[e] = (f16)(y2 * ca[e] + y1 * sa[e]);
    }
    *(half4*)(q + (size_t)row * S_DIM + j0) = ql;
    *(half4*)(q + (size_t)row * S_DIM + j0 + HALF) = qh;
    *(half4*)(kq + (size_t)row * S_DIM + j0) = kl;
    *(half4*)(kq + (size_t)row * S_DIM + j0 + HALF) = kh;
}

// ---------------- GEMM 2: two kern chunks per launch (z = b + 4*half) ------
__global__ __launch_bounds__(256) void k_mm_qk(const f16* __restrict__ q,
                                               const f16* __restrict__ k,
                                               f16* __restrict__ kc0,
                                               f16* __restrict__ kc1, int pair) {
    __shared__ f16 stage[256 * 64];
    const int b = blockIdx.z & 3;
    const int half = blockIdx.z >> 2;
    f16* kern = half ? kc1 : kc0;
    const int mc = pair * 2 + half;
    const int m0 = blockIdx.y * 128, n0 = blockIdx.x * 128;
    f32x4 acc[4][4];
#pragma unroll
    for (int i = 0; i < 4; ++i)
#pragma unroll
        for (int j = 0; j < 4; ++j) acc[i][j] = (f32x4){0.f, 0.f, 0.f, 0.f};
    const char* Ab = (const char*)(q + (size_t)(b * L_DIM + mc * 1024 + m0) * S_DIM);
    const char* Bb = (const char*)(k + (size_t)(b * L_DIM + n0) * S_DIM);
    mfma_core<4, 4>(Ab, S_DIM * 2, Bb, S_DIM * 2, S_DIM, stage, acc);
    const int lane = threadIdx.x & 63, wv = threadIdx.x >> 6;
    const int wr = wv >> 1, wc = wv & 1;
#pragma unroll
    for (int mt = 0; mt < 4; ++mt)
#pragma unroll
        for (int nt = 0; nt < 4; ++nt)
#pragma unroll
            for (int r = 0; r < 4; ++r) {
                int ml = wr * 64 + mt * 16 + (lane >> 4) * 4 + r;
                int nl = wc * 64 + nt * 16 + (lane & 15);
                float t = fmaxf(acc[mt][nt][r] * INV_SQRT_S, 0.f);
                t = fminf(t, 240.f);  // fp16-range guard (inert on real data)
                kern[(size_t)(b * 1024 + m0 + ml) * L_DIM + (n0 + nl)] = (f16)(t * t);
            }
}

// ---------------- GEMM 3: aub = u ⊙ (kern @ v), r8 dbuf core ---------------
// blockIdx.x = m-tile so id%8 == m-tile -> kern A-panel XCD-local.
__global__ __launch_bounds__(256) void k_mm_av(const f16* __restrict__ kc0,
                                               const f16* __restrict__ kc1,
                                               const f16* __restrict__ vT,
                                               const f16* __restrict__ u,
                                               f16* __restrict__ aub, int pair) {
    __shared__ union {
        struct { char s0[32768]; char s1[32768]; } st;
        f16 tr[128][136];
    } sl;
    const int b = blockIdx.z & 3;
    const int half = blockIdx.z >> 2;
    const f16* kern = half ? kc1 : kc0;
    const int mc = pair * 2 + half;
    const int m0 = blockIdx.x * 128, n0 = blockIdx.y * 128;  // x <-> m (XCD locality)
    f32x4 acc[4][4];
#pragma unroll
    for (int i = 0; i < 4; ++i)
#pragma unroll
        for (int j = 0; j < 4; ++j) acc[i][j] = (f32x4){0.f, 0.f, 0.f, 0.f};
    const char* Ab = (const char*)(kern + (size_t)(b * 1024 + m0) * L_DIM);
    const char* Bb = (const char*)(vT + ((size_t)b * E_DIM + n0) * L_DIM);
    mfma_core_db<4, 4>(Ab, L_DIM * 2, Bb, L_DIM * 2, L_DIM, sl.st.s0, sl.st.s1, acc);
    const int lane = threadIdx.x & 63, wv = threadIdx.x >> 6;
    const int wr = wv >> 1, wc = wv & 1;
#pragma unroll
    for (int nt = 0; nt < 4; ++nt) {
        int nl = wc * 64 + nt * 16 + (lane & 15);
#pragma unroll
        for (int mt = 0; mt < 4; ++mt)
#pragma unroll
            for (int r = 0; r < 4; ++r) {
                int ml = wr * 64 + mt * 16 + (lane >> 4) * 4 + r;
                sl.tr[ml][nl] = (f16)acc[mt][nt][r];
            }
    }
    __syncthreads();
    int rl = threadIdx.x >> 1, h = threadIdx.x & 1;
    size_t mg = (size_t)b * L_DIM + (size_t)mc * 1024 + m0 + rl;
    const f16* up = u + mg * E_DIM + n0 + h * 64;
    f16* ap = aub + mg * E_DIM + n0 + h * 64;
#pragma unroll
    for (int i = 0; i < 8; ++i) {
        half8 s8 = *(const half8*)&sl.tr[rl][h * 64 + i * 8];
        half8 u8 = *(const half8*)(up + i * 8);
        half8 o8;
#pragma unroll
        for (int j = 0; j < 8; ++j) {
            float val = (float)s8[j] * (float)u8[j];
            val = fminf(fmaxf(val, -60000.f), 60000.f);  // fp16-range guard
            o8[j] = (f16)val;
        }
        *(half8*)(ap + i * 8) = o8;
    }
}

// ---------------- GEMM 4: out = aub @ o_w^T + o_b + x (r8 dbuf) ------------
__global__ __launch_bounds__(256) void k_mm_out(const f16* __restrict__ aub,
                                                const f16* __restrict__ wo,
                                                const float* __restrict__ ob,
                                                const float* __restrict__ x,
                                                float* __restrict__ out) {
    __shared__ char s0[32768];
    __shared__ char s1[32768];
    const int m0 = blockIdx.y * 128, n0 = blockIdx.x * 128;
    f32x4 acc[4][4];
#pragma unroll
    for (int i = 0; i < 4; ++i)
#pragma unroll
        for (int j = 0; j < 4; ++j) acc[i][j] = (f32x4){0.f, 0.f, 0.f, 0.f};
    mfma_core_db<4, 4>((const char*)(aub + (size_t)m0 * E_DIM), E_DIM * 2,
                       (const char*)(wo + (size_t)n0 * E_DIM), E_DIM * 2,
                       E_DIM, s0, s1, acc);
    const int lane = threadIdx.x & 63, wv = threadIdx.x >> 6;
    const int wr = wv >> 1, wc = wv & 1;
#pragma unroll
    for (int nt = 0; nt < 4; ++nt) {
        int nl = wc * 64 + nt * 16 + (lane & 15);
        float obv = ob[n0 + nl];
#pragma unroll
        for (int mt = 0; mt < 4; ++mt)
#pragma unroll
            for (int r = 0; r < 4; ++r) {
                int ml = wr * 64 + mt * 16 + (lane >> 4) * 4 + r;
                size_t m = m0 + ml;
                size_t n = n0 + nl;
                out[m * H_DIM + n] = acc[mt][nt][r] + obv + x[m * H_DIM + n];
            }
    }
}

extern "C" void kernel_launch(void* const* d_in, const int* in_sizes, int n_in,
                              void* d_out, int out_size, void* d_ws, size_t ws_size,
                              hipStream_t stream) {
    const float* x     = (const float*)d_in[0];
    const float* ln_w  = (const float*)d_in[1];
    const float* ln_b  = (const float*)d_in[2];
    const float* uv_w  = (const float*)d_in[3];
    const float* uv_b  = (const float*)d_in[4];
    const float* gamma = (const float*)d_in[5];
    const float* beta  = (const float*)d_in[6];
    const float* o_w   = (const float*)d_in[7];
    const float* o_b   = (const float*)d_in[8];
    float* out = (float*)d_out;
    char* ws = (char*)d_ws;

    f16* wuv  = (f16*)(ws + OFF_WUV);
    f16* wo   = (f16*)(ws + OFF_WO);
    f16* u    = (f16*)(ws + OFF_U);
    f16* vT   = (f16*)(ws + OFF_VT);
    f16* aub  = (f16*)(ws + OFF_AUB);
    f16* q    = (f16*)(ws + OFF_Q);
    f16* k    = (f16*)(ws + OFF_K);
    f16* kc0  = (f16*)(ws + OFF_KC0);
    f16* kc1  = (f16*)(ws + OFF_KC1);
    f16* xn   = (f16*)(ws + OFF_XN);
    float* cosT = (float*)(ws + OFF_COS);
    float* sinT = (float*)(ws + OFF_SIN);
    float* braw = (float*)(ws + OFF_BR);

    k_pre<<<6720, 256, 0, stream>>>(x, ln_w, ln_b, xn, uv_w, o_w, wuv, wo,
                                    cosT, sinT);
    k_mm_uv<<<dim3(17, 128), 256, 0, stream>>>(xn, wuv, uv_b, u, vT, braw);
    k_prep<<<1024, 256, 0, stream>>>(braw, gamma, beta, cosT, sinT, q, k);
    // xn (aliased with kc1) is dead from here; qk(half=1) may overwrite it.
    for (int pair = 0; pair < 2; ++pair) {
        k_mm_qk<<<dim3(32, 8, 8), 256, 0, stream>>>(q, k, kc0, kc1, pair);
        k_mm_av<<<dim3(8, 8, 8), 256, 0, stream>>>(kc0, kc1, vT, u, aub, pair);
    }
    k_mm_out<<<dim3(4, 128), 256, 0, stream>>>(aub, wo, o_b, x, out);
}

// Round 15
// 323.022 us; speedup vs baseline: 1.1251x; 1.0137x over previous
//
#include <hip/hip_runtime.h>
#include <math.h>

// Problem constants
#define L_DIM 4096
#define B_DIM 4
#define H_DIM 512
#define E_DIM 1024
#define S_DIM 128
#define HALF  64
#define N_ROWS 16384
#define NUV   2176
#define LN_EPS 1e-5f
#define INV_SQRT_S 0.08838834764831845f

typedef _Float16 f16;
typedef __attribute__((ext_vector_type(8))) _Float16 half8;
typedef __attribute__((ext_vector_type(4))) _Float16 half4;
typedef __attribute__((ext_vector_type(4))) float f32x4;

// fast silu: v_exp_f32 + v_rcp_f32 — safe only with VGPR pinned (LB 256,4)
__device__ __forceinline__ float fast_silu(float s) {
    return s * __builtin_amdgcn_rcpf(1.f + __expf(-s));
}

// ---------------- workspace byte offsets ----------------
// FULL kern (no chunking). xn aliases kern's head (xn dead before qk writes;
// both touched only via global_load_lds / plain stores — proven discipline).
// Capacity probe: end = 245.1 MiB. Known: 186.1 fits, 266.1 aborts.
#define OFF_WUV  ((size_t)0)                        // f16 [2176][512]   2.2 MB
#define OFF_WO   (OFF_WUV + 2228224)                // f16 [512][1024]   1 MB
#define OFF_U    (OFF_WO + 1048576)                 // f16 [16384][1024] 32 MB
#define OFF_VT   (OFF_U + 33554432)                 // f16 [4][1024][4096] 32 MB
#define OFF_AUB  (OFF_VT + 33554432)                // f16 [16384][1024] 32 MB
#define OFF_Q    (OFF_AUB + 33554432)               // f16 [16384][128]  4 MB
#define OFF_K    (OFF_Q + 4194304)                  // f16 [16384][128]  4 MB
#define OFF_KERN (OFF_K + 4194304)                  // f16 [4][4096][4096] 128 MB
#define OFF_XN   OFF_KERN                           // f16 [16384][512] (aliased)
#define OFF_COS  (OFF_KERN + 134217728)             // f32 [4096][64]   1 MB
#define OFF_SIN  (OFF_COS + 1048576)                // f32 [4096][64]   1 MB
#define OFF_BR   (OFF_SIN + 1048576)                // f32 [16384][128] 8 MB
// end = OFF_BR + 8 MB = 257,032,192 B = 245.1 MiB

// ---------------- merged prologue: LN+cvt (xn | weights | rope tables) -----
__global__ __launch_bounds__(256) void k_pre(const float* __restrict__ x,
                                             const float* __restrict__ lnw,
                                             const float* __restrict__ lnb,
                                             f16* __restrict__ xn,
                                             const float* __restrict__ uvw,
                                             const float* __restrict__ ow,
                                             f16* __restrict__ duv,
                                             f16* __restrict__ dow,
                                             float* __restrict__ cosT,
                                             float* __restrict__ sinT) {
    const int bid = blockIdx.x;
    if (bid < 4096) {  // ---- LN + f16 convert ----
        int row = bid * 4 + (threadIdx.x >> 6);
        int lane = threadIdx.x & 63;
        const float4* xr = (const float4*)(x + (size_t)row * H_DIM);
        float4 a = xr[lane * 2], b = xr[lane * 2 + 1];
        float s = a.x + a.y + a.z + a.w + b.x + b.y + b.z + b.w;
        float s2 = a.x * a.x + a.y * a.y + a.z * a.z + a.w * a.w
                 + b.x * b.x + b.y * b.y + b.z * b.z + b.w * b.w;
#pragma unroll
        for (int off = 32; off > 0; off >>= 1) {
            s  += __shfl_xor(s, off);
            s2 += __shfl_xor(s2, off);
        }
        float m = s / (float)H_DIM;
        float var = s2 / (float)H_DIM - m * m;
        float r = rsqrtf(var + LN_EPS);
        const float4* wr4 = (const float4*)lnw;
        const float4* br4 = (const float4*)lnb;
        float4 wa = wr4[lane * 2], wb = wr4[lane * 2 + 1];
        float4 ba = br4[lane * 2], bb = br4[lane * 2 + 1];
        half8 o;
        o[0] = (f16)((a.x - m) * r * wa.x + ba.x);
        o[1] = (f16)((a.y - m) * r * wa.y + ba.y);
        o[2] = (f16)((a.z - m) * r * wa.z + ba.z);
        o[3] = (f16)((a.w - m) * r * wa.w + ba.w);
        o[4] = (f16)((b.x - m) * r * wb.x + bb.x);
        o[5] = (f16)((b.y - m) * r * wb.y + bb.y);
        o[6] = (f16)((b.z - m) * r * wb.z + bb.z);
        o[7] = (f16)((b.w - m) * r * wb.w + bb.w);
        *(half8*)(xn + (size_t)row * H_DIM + lane * 8) = o;
    } else if (bid < 5696) {  // ---- weight conversion (uv_w then o_w) ----
        int gid = (bid - 4096) * 256 + threadIdx.x;
        int i4 = gid << 2;
        const float* src;
        f16* dst;
        int off;
        if (i4 < NUV * H_DIM) { src = uvw; dst = duv; off = i4; }
        else { src = ow; dst = dow; off = i4 - NUV * H_DIM; }
        float4 v = *(const float4*)(src + off);
        half4 o = {(f16)v.x, (f16)v.y, (f16)v.z, (f16)v.w};
        *(half4*)(dst + off) = o;
    } else {  // ---- RoPE cos/sin tables ----
        int idx = (bid - 5696) * 256 + threadIdx.x;
        int pos = idx >> 6;
        int j = idx & 63;
        float invf = (float)pow(10000.0, (double)j / 64.0);
        float angf = (float)pos * invf;
        double ang = (double)angf;
        cosT[idx] = (float)cos(ang);
        sinT[idx] = (float)sin(ang);
    }
}

// ---------------- MFMA cores: C = A · B^T (both K-major f16) ----------------
__device__ __forceinline__ void gload16(const void* g, void* l) {
    __builtin_amdgcn_global_load_lds(
        (const __attribute__((address_space(1))) unsigned int*)g,
        (__attribute__((address_space(3))) unsigned int*)l, 16, 0, 0);
}

// Single-buffer core (hoisted addressing) — for uv (4 blocks/CU) & qk.
template <int MT, int NT>
__device__ __forceinline__ void mfma_core(const char* Ab, int lda_b,
                                          const char* Bb, int ldb_b,
                                          int K, f16* lds, f32x4 acc[MT][NT]) {
    constexpr int BM = 32 * MT, BN = 32 * NT;
    constexpr int ISS = (BM + BN) / 32;
    constexpr int ASLOTS = (BM * 128) / 1024;
    const int tid = threadIdx.x;
    const int lane = tid & 63;
    const int wv = tid >> 6;
    const int wr = wv >> 1, wc = wv & 1;
    char* ldsc = (char*)lds;

    const char* sb[ISS];
    unsigned voff[ISS];
#pragma unroll
    for (int i = 0; i < ISS; ++i) {
        const int slot = wv * ISS + i;
        const int ell = (slot << 10) + (lane << 4);
        if (slot < ASLOTS) {
            int row = ell >> 7, kb = ell & 127;
            sb[i] = Ab;
            voff[i] = (unsigned)row * (unsigned)lda_b + (unsigned)(kb ^ ((row & 7) << 4));
        } else {
            const int e2 = ell - BM * 128;
            int row = e2 >> 7, kb = e2 & 127;
            sb[i] = Bb;
            voff[i] = (unsigned)row * (unsigned)ldb_b + (unsigned)(kb ^ ((row & 7) << 4));
        }
    }
    unsigned aoff[MT], boff[NT];
#pragma unroll
    for (int mt = 0; mt < MT; ++mt) {
        int row = wr * (MT * 16) + mt * 16 + (lane & 15);
        unsigned byt = (unsigned)((row << 7) + ((lane >> 4) << 4));
        aoff[mt] = byt ^ (unsigned)((row & 7) << 4);
    }
#pragma unroll
    for (int nt = 0; nt < NT; ++nt) {
        int row = wc * (NT * 16) + nt * 16 + (lane & 15);
        unsigned byt = (unsigned)((row << 7) + ((lane >> 4) << 4));
        boff[nt] = (byt ^ (unsigned)((row & 7) << 4)) + (unsigned)(BM * 128);
    }

    for (int k0 = 0; k0 < K; k0 += 64) {
        const unsigned kbyte = (unsigned)(k0 << 1);
#pragma unroll
        for (int i = 0; i < ISS; ++i)
            gload16(sb[i] + voff[i] + kbyte, ldsc + ((wv * ISS + i) << 10));
        __syncthreads();
#pragma unroll
        for (int ks = 0; ks < 2; ++ks) {
            half8 af[MT], bf[NT];
#pragma unroll
            for (int mt = 0; mt < MT; ++mt)
                af[mt] = *(const half8*)(ldsc + (aoff[mt] ^ (unsigned)(ks << 6)));
#pragma unroll
            for (int nt = 0; nt < NT; ++nt)
                bf[nt] = *(const half8*)(ldsc + (boff[nt] ^ (unsigned)(ks << 6)));
#pragma unroll
            for (int mt = 0; mt < MT; ++mt)
#pragma unroll
                for (int nt = 0; nt < NT; ++nt)
                    acc[mt][nt] = __builtin_amdgcn_mfma_f32_16x16x32_f16(af[mt], bf[nt], acc[mt][nt], 0, 0, 0);
        }
        __syncthreads();
    }
}

// 2-phase dbuf core (r8-proven, A+B staged) — for av & out.
template <int MT, int NT>
__device__ __forceinline__ void mfma_core_db(const char* Ab, int lda_b,
                                             const char* Bb, int ldb_b,
                                             int K, char* l0, char* l1,
                                             f32x4 acc[MT][NT]) {
    constexpr int BM = 32 * MT, BN = 32 * NT;
    constexpr int ISS = (BM + BN) / 32;
    constexpr int ASLOTS = (BM * 128) / 1024;
    const int tid = threadIdx.x;
    const int lane = tid & 63;
    const int wv = tid >> 6;
    const int wr = wv >> 1, wc = wv & 1;

    const char* sb[ISS];
    unsigned voff[ISS];
#pragma unroll
    for (int i = 0; i < ISS; ++i) {
        const int slot = wv * ISS + i;
        const int ell = (slot << 10) + (lane << 4);
        if (slot < ASLOTS) {
            int row = ell >> 7, kb = ell & 127;
            sb[i] = Ab;
            voff[i] = (unsigned)row * (unsigned)lda_b + (unsigned)(kb ^ ((row & 7) << 4));
        } else {
            const int e2 = ell - BM * 128;
            int row = e2 >> 7, kb = e2 & 127;
            sb[i] = Bb;
            voff[i] = (unsigned)row * (unsigned)ldb_b + (unsigned)(kb ^ ((row & 7) << 4));
        }
    }
    unsigned aoff[MT], boff[NT];
#pragma unroll
    for (int mt = 0; mt < MT; ++mt) {
        int row = wr * (MT * 16) + mt * 16 + (lane & 15);
        unsigned byt = (unsigned)((row << 7) + ((lane >> 4) << 4));
        aoff[mt] = byt ^ (unsigned)((row & 7) << 4);
    }
#pragma unroll
    for (int nt = 0; nt < NT; ++nt) {
        int row = wc * (NT * 16) + nt * 16 + (lane & 15);
        unsigned byt = (unsigned)((row << 7) + ((lane >> 4) << 4));
        boff[nt] = (byt ^ (unsigned)((row & 7) << 4)) + (unsigned)(BM * 128);
    }

    auto stage = [&](char* dst, unsigned kbyte) {
#pragma unroll
        for (int i = 0; i < ISS; ++i)
            gload16(sb[i] + voff[i] + kbyte, dst + ((wv * ISS + i) << 10));
    };
    auto compute = [&](const char* src) {
#pragma unroll
        for (int ks = 0; ks < 2; ++ks) {
            half8 af[MT], bf[NT];
#pragma unroll
            for (int mt = 0; mt < MT; ++mt)
                af[mt] = *(const half8*)(src + (aoff[mt] ^ (unsigned)(ks << 6)));
#pragma unroll
            for (int nt = 0; nt < NT; ++nt)
                bf[nt] = *(const half8*)(src + (boff[nt] ^ (unsigned)(ks << 6)));
#pragma unroll
            for (int mt = 0; mt < MT; ++mt)
#pragma unroll
                for (int nt = 0; nt < NT; ++nt)
                    acc[mt][nt] = __builtin_amdgcn_mfma_f32_16x16x32_f16(af[mt], bf[nt], acc[mt][nt], 0, 0, 0);
        }
    };

    const int nst = K / 64;  // even
    stage(l0, 0u);
    __syncthreads();
    for (int t = 0; t < nst; t += 2) {
        stage(l1, (unsigned)(t + 1) * 128u);   // prefetch t+1 while computing t
        compute(l0);
        __syncthreads();
        if (t + 2 < nst) stage(l0, (unsigned)(t + 2) * 128u);
        compute(l1);
        __syncthreads();
    }
}

// ---------------- GEMM 1: silu(LN(x)@uv_w^T + b) -> u | vT | braw ----------
__global__ __launch_bounds__(256, 4) void k_mm_uv(const f16* __restrict__ xn,
                                                  const f16* __restrict__ wuv,
                                                  const float* __restrict__ bias,
                                                  f16* __restrict__ u,
                                                  f16* __restrict__ vT,
                                                  float* __restrict__ braw) {
    __shared__ union {
        f16 stage[256 * 64];
        f16 tr[128][136];
    } sl;
    const int m0 = blockIdx.y * 128, n0 = blockIdx.x * 128;
    f32x4 acc[4][4];
#pragma unroll
    for (int i = 0; i < 4; ++i)
#pragma unroll
        for (int j = 0; j < 4; ++j) acc[i][j] = (f32x4){0.f, 0.f, 0.f, 0.f};
    mfma_core<4, 4>((const char*)(xn + (size_t)m0 * H_DIM), H_DIM * 2,
                    (const char*)(wuv + (size_t)n0 * H_DIM), H_DIM * 2,
                    H_DIM, sl.stage, acc);
    const int lane = threadIdx.x & 63, wv = threadIdx.x >> 6;
    const int wr = wv >> 1, wc = wv & 1;
    if (n0 < E_DIM) {  // u region -> LDS tile -> coalesced wide stores
#pragma unroll
        for (int nt = 0; nt < 4; ++nt) {
            int nl = wc * 64 + nt * 16 + (lane & 15);
            float bs = bias[n0 + nl];
#pragma unroll
            for (int mt = 0; mt < 4; ++mt)
#pragma unroll
                for (int r = 0; r < 4; ++r) {
                    int ml = wr * 64 + mt * 16 + (lane >> 4) * 4 + r;
                    sl.tr[ml][nl] = (f16)fast_silu(acc[mt][nt][r] + bs);
                }
        }
        __syncthreads();
        int rl = threadIdx.x >> 1, h = threadIdx.x & 1;
        f16* dst = u + (size_t)(m0 + rl) * E_DIM + n0 + h * 64;
#pragma unroll
        for (int i = 0; i < 8; ++i)
            *(uint4*)(dst + i * 8) = *(const uint4*)&sl.tr[rl][h * 64 + i * 8];
    } else if (n0 < 2 * E_DIM) {  // v region -> transposed store via LDS
#pragma unroll
        for (int nt = 0; nt < 4; ++nt) {
            int nl = wc * 64 + nt * 16 + (lane & 15);
            float bs = bias[n0 + nl];
#pragma unroll
            for (int mt = 0; mt < 4; ++mt)
#pragma unroll
                for (int r = 0; r < 4; ++r) {
                    int ml = wr * 64 + mt * 16 + (lane >> 4) * 4 + r;
                    sl.tr[nl][ml] = (f16)fast_silu(acc[mt][nt][r] + bs);
                }
        }
        __syncthreads();
        int rl = threadIdx.x >> 1, h = threadIdx.x & 1;
        int b = m0 >> 12;
        int mloc = m0 & (L_DIM - 1);
        size_t e = (size_t)(n0 - E_DIM) + rl;
        f16* dst = vT + ((size_t)b * E_DIM + e) * L_DIM + mloc + h * 64;
#pragma unroll
        for (int i = 0; i < 8; ++i)
            *(uint4*)(dst + i * 8) = *(const uint4*)&sl.tr[rl][h * 64 + i * 8];
    } else {  // braw region (f32, 1/17 of blocks)
#pragma unroll
        for (int nt = 0; nt < 4; ++nt) {
            int nl = wc * 64 + nt * 16 + (lane & 15);
            float bs = bias[n0 + nl];
#pragma unroll
            for (int mt = 0; mt < 4; ++mt)
#pragma unroll
                for (int r = 0; r < 4; ++r) {
                    int ml = wr * 64 + mt * 16 + (lane >> 4) * 4 + r;
                    braw[(size_t)(m0 + ml) * S_DIM + (n0 - 2 * E_DIM + nl)] =
                        fast_silu(acc[mt][nt][r] + bs);
                }
        }
    }
}

// ---------------- gamma/beta + RoPE -> q, k (f16), vectorized --------------
__global__ __launch_bounds__(256) void k_prep(const float* __restrict__ braw,
                                              const float* __restrict__ gamma,
                                              const float* __restrict__ beta,
                                              const float* __restrict__ cosT,
                                              const float* __restrict__ sinT,
                                              f16* __restrict__ q,
                                              f16* __restrict__ kq) {
    int idx = blockIdx.x * 256 + threadIdx.x;
    int row = idx >> 4;
    int j0 = (idx & 15) << 2;
    int l = row & (L_DIM - 1);
    float4 b1 = *(const float4*)(braw + (size_t)row * S_DIM + j0);
    float4 b2 = *(const float4*)(braw + (size_t)row * S_DIM + j0 + HALF);
    float4 cv = *(const float4*)(cosT + l * HALF + j0);
    float4 sv = *(const float4*)(sinT + l * HALF + j0);
    float4 g1 = *(const float4*)(gamma + j0);
    float4 g2 = *(const float4*)(gamma + j0 + 64);
    float4 g3 = *(const float4*)(gamma + 128 + j0);
    float4 g4 = *(const float4*)(gamma + 192 + j0);
    float4 e1 = *(const float4*)(beta + j0);
    float4 e2 = *(const float4*)(beta + j0 + 64);
    float4 e3 = *(const float4*)(beta + 128 + j0);
    float4 e4 = *(const float4*)(beta + 192 + j0);
    const float* b1a = (const float*)&b1;
    const float* b2a = (const float*)&b2;
    const float* ca = (const float*)&cv;
    const float* sa = (const float*)&sv;
    const float* g1a = (const float*)&g1;
    const float* g2a = (const float*)&g2;
    const float* g3a = (const float*)&g3;
    const float* g4a = (const float*)&g4;
    const float* e1a = (const float*)&e1;
    const float* e2a = (const float*)&e2;
    const float* e3a = (const float*)&e3;
    const float* e4a = (const float*)&e4;
    half4 ql, qh, kl, kh;
#pragma unroll
    for (int e = 0; e < 4; ++e) {
        float x1 = b1a[e] * g1a[e] + e1a[e];
        float x2 = b2a[e] * g2a[e] + e2a[e];
        ql[e] = (f16)(x1 * ca[e] - x2 * sa[e]);
        qh[e] = (f16)(x2 * ca[e] + x1 * sa[e]);
        float y1 = b1a[e] * g3a[e] + e3a[e];
        float y2 = b2a[e] * g4a[e] + e4a[e];
        kl[e] = (f16)(y1 * ca[e] - y2 * sa[e]);
        kh[e] = (f16)(y2 * ca[e] + y1 * sa[e]);
    }
    *(half4*)(q + (size_t)row * S_DIM + j0) = ql;
    *(half4*)(q + (size_t)row * S_DIM + j0 + HALF) = qh;
    *(half4*)(kq + (size_t)row * S_DIM + j0) = kl;
    *(half4*)(kq + (size_t)row * S_DIM + j0 + HALF) = kh;
}

// ---------------- GEMM 2: full kern in one launch (z = batch) --------------
__global__ __launch_bounds__(256) void k_mm_qk(const f16* __restrict__ q,
                                               const f16* __restrict__ k,
                                               f16* __restrict__ kern) {
    __shared__ f16 stage[256 * 64];
    const int b = blockIdx.z;
    const int m0 = blockIdx.y * 128, n0 = blockIdx.x * 128;
    f32x4 acc[4][4];
#pragma unroll
    for (int i = 0; i < 4; ++i)
#pragma unroll
        for (int j = 0; j < 4; ++j) acc[i][j] = (f32x4){0.f, 0.f, 0.f, 0.f};
    const char* Ab = (const char*)(q + (size_t)(b * L_DIM + m0) * S_DIM);
    const char* Bb = (const char*)(k + (size_t)(b * L_DIM + n0) * S_DIM);
    mfma_core<4, 4>(Ab, S_DIM * 2, Bb, S_DIM * 2, S_DIM, stage, acc);
    const int lane = threadIdx.x & 63, wv = threadIdx.x >> 6;
    const int wr = wv >> 1, wc = wv & 1;
#pragma unroll
    for (int mt = 0; mt < 4; ++mt)
#pragma unroll
        for (int nt = 0; nt < 4; ++nt)
#pragma unroll
            for (int r = 0; r < 4; ++r) {
                int ml = wr * 64 + mt * 16 + (lane >> 4) * 4 + r;
                int nl = wc * 64 + nt * 16 + (lane & 15);
                float t = fmaxf(acc[mt][nt][r] * INV_SQRT_S, 0.f);
                t = fminf(t, 240.f);  // fp16-range guard (inert on real data)
                kern[((size_t)b * L_DIM + m0 + ml) * L_DIM + (n0 + nl)] = (f16)(t * t);
            }
}

// ---------------- GEMM 3: aub = u ⊙ (kern @ v), r8 dbuf core, one launch ---
// blockIdx.x = m-tile (32) so id%8 cycles XCDs over m-tiles: per XCD only
// m-tiles ≡ xcd (mod 8) -> 4 kern panels (4 MB) per (y,z) slice, L2-resident.
__global__ __launch_bounds__(256) void k_mm_av(const f16* __restrict__ kern,
                                               const f16* __restrict__ vT,
                                               const f16* __restrict__ u,
                                               f16* __restrict__ aub) {
    __shared__ union {
        struct { char s0[32768]; char s1[32768]; } st;
        f16 tr[128][136];
    } sl;
    const int b = blockIdx.z;
    const int m0 = blockIdx.x * 128, n0 = blockIdx.y * 128;  // x <-> m (XCD locality)
    f32x4 acc[4][4];
#pragma unroll
    for (int i = 0; i < 4; ++i)
#pragma unroll
        for (int j = 0; j < 4; ++j) acc[i][j] = (f32x4){0.f, 0.f, 0.f, 0.f};
    const char* Ab = (const char*)(kern + ((size_t)b * L_DIM + m0) * L_DIM);
    const char* Bb = (const char*)(vT + ((size_t)b * E_DIM + n0) * L_DIM);
    mfma_core_db<4, 4>(Ab, L_DIM * 2, Bb, L_DIM * 2, L_DIM, sl.st.s0, sl.st.s1, acc);
    const int lane = threadIdx.x & 63, wv = threadIdx.x >> 6;
    const int wr = wv >> 1, wc = wv & 1;
#pragma unroll
    for (int nt = 0; nt < 4; ++nt) {
        int nl = wc * 64 + nt * 16 + (lane & 15);
#pragma unroll
        for (int mt = 0; mt < 4; ++mt)
#pragma unroll
            for (int r = 0; r < 4; ++r) {
                int ml = wr * 64 + mt * 16 + (lane >> 4) * 4 + r;
                sl.tr[ml][nl] = (f16)acc[mt][nt][r];
            }
    }
    __syncthreads();
    int rl = threadIdx.x >> 1, h = threadIdx.x & 1;
    size_t mg = (size_t)b * L_DIM + m0 + rl;
    const f16* up = u + mg * E_DIM + n0 + h * 64;
    f16* ap = aub + mg * E_DIM + n0 + h * 64;
#pragma unroll
    for (int i = 0; i < 8; ++i) {
        half8 s8 = *(const half8*)&sl.tr[rl][h * 64 + i * 8];
        half8 u8 = *(const half8*)(up + i * 8);
        half8 o8;
#pragma unroll
        for (int j = 0; j < 8; ++j) {
            float val = (float)s8[j] * (float)u8[j];
            val = fminf(fmaxf(val, -60000.f), 60000.f);  // fp16-range guard
            o8[j] = (f16)val;
        }
        *(half8*)(ap + i * 8) = o8;
    }
}

// ---------------- GEMM 4: out = aub @ o_w^T + o_b + x (r8 dbuf) ------------
__global__ __launch_bounds__(256) void k_mm_out(const f16* __restrict__ aub,
                                                const f16* __restrict__ wo,
                                                const float* __restrict__ ob,
                                                const float* __restrict__ x,
                                                float* __restrict__ out) {
    __shared__ char s0[32768];
    __shared__ char s1[32768];
    const int m0 = blockIdx.y * 128, n0 = blockIdx.x * 128;
    f32x4 acc[4][4];
#pragma unroll
    for (int i = 0; i < 4; ++i)
#pragma unroll
        for (int j = 0; j < 4; ++j) acc[i][j] = (f32x4){0.f, 0.f, 0.f, 0.f};
    mfma_core_db<4, 4>((const char*)(aub + (size_t)m0 * E_DIM), E_DIM * 2,
                       (const char*)(wo + (size_t)n0 * E_DIM), E_DIM * 2,
                       E_DIM, s0, s1, acc);
    const int lane = threadIdx.x & 63, wv = threadIdx.x >> 6;
    const int wr = wv >> 1, wc = wv & 1;
#pragma unroll
    for (int nt = 0; nt < 4; ++nt) {
        int nl = wc * 64 + nt * 16 + (lane & 15);
        float obv = ob[n0 + nl];
#pragma unroll
        for (int mt = 0; mt < 4; ++mt)
#pragma unroll
            for (int r = 0; r < 4; ++r) {
                int ml = wr * 64 + mt * 16 + (lane >> 4) * 4 + r;
                size_t m = m0 + ml;
                size_t n = n0 + nl;
                out[m * H_DIM + n] = acc[mt][nt][r] + obv + x[m * H_DIM + n];
            }
    }
}

extern "C" void kernel_launch(void* const* d_in, const int* in_sizes, int n_in,
                              void* d_out, int out_size, void* d_ws, size_t ws_size,
                              hipStream_t stream) {
    const float* x     = (const float*)d_in[0];
    const float* ln_w  = (const float*)d_in[1];
    const float* ln_b  = (const float*)d_in[2];
    const float* uv_w  = (const float*)d_in[3];
    const float* uv_b  = (const float*)d_in[4];
    const float* gamma = (const float*)d_in[5];
    const float* beta  = (const float*)d_in[6];
    const float* o_w   = (const float*)d_in[7];
    const float* o_b   = (const float*)d_in[8];
    float* out = (float*)d_out;
    char* ws = (char*)d_ws;

    f16* wuv  = (f16*)(ws + OFF_WUV);
    f16* wo   = (f16*)(ws + OFF_WO);
    f16* u    = (f16*)(ws + OFF_U);
    f16* vT   = (f16*)(ws + OFF_VT);
    f16* aub  = (f16*)(ws + OFF_AUB);
    f16* q    = (f16*)(ws + OFF_Q);
    f16* k    = (f16*)(ws + OFF_K);
    f16* kern = (f16*)(ws + OFF_KERN);
    f16* xn   = (f16*)(ws + OFF_XN);
    float* cosT = (float*)(ws + OFF_COS);
    float* sinT = (float*)(ws + OFF_SIN);
    float* braw = (float*)(ws + OFF_BR);

    k_pre<<<6720, 256, 0, stream>>>(x, ln_w, ln_b, xn, uv_w, o_w, wuv, wo,
                                    cosT, sinT);
    k_mm_uv<<<dim3(17, 128), 256, 0, stream>>>(xn, wuv, uv_b, u, vT, braw);
    k_prep<<<1024, 256, 0, stream>>>(braw, gamma, beta, cosT, sinT, q, k);
    // xn (aliased with kern's head) is dead from here; qk overwrites it.
    k_mm_qk<<<dim3(32, 32, 4), 256, 0, stream>>>(q, k, kern);
    k_mm_av<<<dim3(32, 8, 4), 256, 0, stream>>>(kern, vT, u, aub);
    k_mm_out<<<dim3(4, 128), 256, 0, stream>>>(aub, wo, o_b, x, out);
}